// Round 5
// baseline (970.394 us; speedup 1.0000x reference)
//
#include <hip/hip_runtime.h>
#include <hip/hip_bf16.h>

#define T_TOK 4096
#define DDIM  2048
#define FDIM  4096
#define NEXP  8
#define MAXROWS 9216   // T*2 + 8*128 padding (128-grain segments)
#define MAXMT   72     // MAXROWS/128 (gemm2 m-tiles)
#define NT256   40     // max 256-grain m-tiles: sum ceil(seg/256) <= 40

typedef __attribute__((ext_vector_type(4))) float f32x4;
typedef __attribute__((ext_vector_type(8))) short bf16x8;

__device__ __forceinline__ unsigned short f2b(float f) {
  union { float f; unsigned u; } c; c.f = f;
  unsigned r = c.u + 0x7FFFu + ((c.u >> 16) & 1u);
  return (unsigned short)(r >> 16);
}

// async global->LDS, 16B per lane; LDS dest must be wave-uniform base (+lane*16 implicit)
__device__ __forceinline__ void gload_lds16(const void* g, void* l) {
  __builtin_amdgcn_global_load_lds((__attribute__((address_space(1))) void*)(g),
                                   (__attribute__((address_space(3))) void*)(l),
                                   16, 0, 0);
}

// ---------------- gating: one wave per token ----------------
__global__ void gate_topk(const float* __restrict__ x, const float* __restrict__ gw,
                          int* __restrict__ sel_e, float* __restrict__ sel_w) {
  const int t = blockIdx.x * 4 + (threadIdx.x >> 6);
  const int l = threadIdx.x & 63;
  const float* xr = x + (size_t)t * DDIM;
  float acc[8];
  #pragma unroll
  for (int e = 0; e < 8; ++e) acc[e] = 0.f;
  for (int d = l; d < DDIM; d += 64) {
    const float xv = xr[d];
    const float* g = gw + d * 8;
    #pragma unroll
    for (int e = 0; e < 8; ++e) acc[e] = fmaf(xv, g[e], acc[e]);
  }
  #pragma unroll
  for (int e = 0; e < 8; ++e) {
    float v = acc[e];
    #pragma unroll
    for (int off = 32; off; off >>= 1) v += __shfl_xor(v, off, 64);
    acc[e] = v;
  }
  if (l == 0) {
    int e0 = 0; float v0 = acc[0];
    #pragma unroll
    for (int e = 1; e < 8; ++e) if (acc[e] > v0) { v0 = acc[e]; e0 = e; }
    int e1 = -1; float v1 = -1e30f;
    #pragma unroll
    for (int e = 0; e < 8; ++e) if (e != e0 && acc[e] > v1) { v1 = acc[e]; e1 = e; }
    const float ex = __expf(v1 - v0);
    const float w0 = 1.f / (1.f + ex);
    sel_e[t * 2] = e0; sel_e[t * 2 + 1] = e1;
    sel_w[t * 2] = w0; sel_w[t * 2 + 1] = ex * w0;
  }
}

// ---------------- per-expert lists (single block) ----------------
__global__ void build_lists(const int* __restrict__ sel_e, const float* __restrict__ sel_w,
                            int* __restrict__ cnt, int* __restrict__ base,
                            int* __restrict__ row_token, float* __restrict__ row_gw,
                            int* __restrict__ tE, int* __restrict__ tM0,
                            int* __restrict__ tEnd) {
  __shared__ int c[8], f[8], b[9];
  const int tid = threadIdx.x;
  if (tid < 8) { c[tid] = 0; f[tid] = 0; }
  __syncthreads();
  for (int t = tid; t < T_TOK; t += 256) {
    atomicAdd(&c[sel_e[t * 2]], 1);
    atomicAdd(&c[sel_e[t * 2 + 1]], 1);
  }
  __syncthreads();
  if (tid == 0) {
    int r = 0;
    for (int e = 0; e < 8; ++e) { b[e] = r; r += ((c[e] + 127) >> 7) << 7; }
    b[8] = r;
    for (int e = 0; e < 8; ++e) { cnt[e] = c[e]; base[e] = b[e]; }
    base[8] = r;
    // 256-grain tile table for gemm1
    int nt = 0;
    for (int e = 0; e < 8; ++e)
      for (int i = b[e]; i < b[e + 1]; i += 256) {
        tE[nt] = e; tM0[nt] = i; tEnd[nt] = b[e + 1]; ++nt;
      }
    for (; nt < NT256; ++nt) { tE[nt] = 0; tM0[nt] = -1; tEnd[nt] = 0; }
  }
  __syncthreads();
  for (int i = tid; i < MAXROWS; i += 256) { row_token[i] = -1; row_gw[i] = 0.f; }
  __syncthreads();
  for (int t = tid; t < T_TOK; t += 256) {
    #pragma unroll
    for (int k = 0; k < 2; ++k) {
      const int e = sel_e[t * 2 + k];
      const int p = b[e] + atomicAdd(&f[e], 1);
      row_token[p] = t; row_gw[p] = sel_w[t * 2 + k];
    }
  }
}

// ---------------- gather x rows -> compact bf16 ----------------
__global__ void gather_x(const float* __restrict__ x, const int* __restrict__ base,
                         const int* __restrict__ row_token, unsigned short* __restrict__ xc) {
  const int i = blockIdx.x;
  if (i >= base[8]) return;
  const int t = row_token[i];
  const int tid = threadIdx.x;
  union { uint4 u; unsigned short s[8]; } o;
  if (t < 0) { o.u.x = 0u; o.u.y = 0u; o.u.z = 0u; o.u.w = 0u; }
  else {
    const float4* src = (const float4*)(x + (size_t)t * DDIM + tid * 8);
    const float4 a = src[0], bb = src[1];
    o.s[0] = f2b(a.x);  o.s[1] = f2b(a.y);  o.s[2] = f2b(a.z);  o.s[3] = f2b(a.w);
    o.s[4] = f2b(bb.x); o.s[5] = f2b(bb.y); o.s[6] = f2b(bb.z); o.s[7] = f2b(bb.w);
  }
  ((uint4*)(xc + (size_t)i * DDIM))[tid] = o.u;
}

// ---------------- transpose + fp32->bf16 convert ----------------
__global__ void conv_t(const float* __restrict__ src, unsigned short* __restrict__ dst,
                       int R, int C, int rowMul, int rowAdd) {
  const int e = blockIdx.z;
  const int r0 = blockIdx.x * 64, c0 = blockIdx.y * 64;
  const float* s = src + (size_t)e * R * C + (size_t)r0 * C + c0;
  unsigned short* d = dst + (size_t)e * R * C * rowMul;
  __shared__ unsigned short T[64][68];
  const int t = threadIdx.x;
  {
    const int i = t >> 2, jb = (t & 3) * 16;
    #pragma unroll
    for (int k2 = 0; k2 < 4; ++k2) {
      const float4 v = *(const float4*)(s + (size_t)i * C + jb + k2 * 4);
      uint2 uu;
      uu.x = (unsigned)f2b(v.x) | ((unsigned)f2b(v.y) << 16);
      uu.y = (unsigned)f2b(v.z) | ((unsigned)f2b(v.w) << 16);
      *(uint2*)&T[i][jb + k2 * 4] = uu;
    }
  }
  __syncthreads();
  {
    const int j = t >> 2, ib = (t & 3) * 16;
    union { uint4 q[2]; unsigned short s16[16]; } pk;
    #pragma unroll
    for (int i = 0; i < 16; ++i) pk.s16[i] = T[ib + i][j];
    unsigned short* drow = d + (size_t)(rowMul * (c0 + j) + rowAdd) * R + r0 + ib;
    *(uint4*)drow = pk.q[0];
    *(uint4*)(drow + 8) = pk.q[1];
  }
}

// ---------------- GEMM1: 256x256 tile, BK=64, 8 waves, deep-pipeline 4-phase ---------
// Slots per buffer: Ah0 = A rows {0-63,128-191}, Ah1 = {64-127,192-255},
//                   Bh0 = B rows {x*64+0..31}, Bh1 = {x*64+32..63}.
// K-tile t (buffer t&1), phases:
//   P1: ds_read Ah0(12 w/ Bh0) -> MFMA quad(h0, nf0-1)
//   P2: ds_read Bh1;  stage Ah0(t+2)->cur   -> quad(h0, nf2-3)
//   P3: ds_read Ah1;  stage Bh0(t+2)->cur   -> quad(h1, nf0-1)
//   P4: stage Bh1(t+2), Ah1(t+2)->cur; s_waitcnt vmcnt(8) -> quad(h1, nf2-3)
// Each slot staged right after its last ds_read of tile t, landing 6-7 phases
// before its first read at tile t+2 (~1800cy >> 900cy HBM). Exactly one counted
// vmcnt per K-tile; loop never drains to 0 (T4). Stage safety: slot's readers
// complete (compiler lgkmcnt before MFMA) before that phase's closing barrier.
__global__ __launch_bounds__(512, 2)
void moe_gemm1(const unsigned short* __restrict__ A,
               const unsigned short* __restrict__ B,
               const int* __restrict__ tE, const int* __restrict__ tM0,
               const int* __restrict__ tEnd,
               unsigned short* __restrict__ hid) {
  __shared__ __align__(16) unsigned short As[2][16384];  // [buf][256 rows][64 k]
  __shared__ __align__(16) unsigned short Bs[2][16384];

  const int nwg = gridDim.x;             // 1280 (= 8*160)
  const int q8 = nwg >> 3;
  const int bid = blockIdx.x;
  const int swz = (bid & 7) * q8 + (bid >> 3);
  const int mt = swz % NT256;            // m-fast: consecutive swz share B-panel
  const int nt = swz / NT256;
  const int m0 = tM0[mt];
  if (m0 < 0) return;
  const int e = tE[mt];
  const int mend = tEnd[mt];
  const int n0 = nt * 256;

  const unsigned short* Bp = B + (size_t)e * (8192ull * 2048ull);

  const int tid = threadIdx.x;
  const int w = tid >> 6;
  const int l = tid & 63;
  const int wm = w >> 2, wn = w & 3;     // 2 x 4 waves, wave tile 128x64
  const int lr = l & 15, kc = l >> 4;

  const int rowT = tid >> 3;             // 0..63
  const int csE = ((tid & 7) ^ (rowT & 7)) << 3;  // swizzled chunk src offset (elems)

  f32x4 acc[8][4];
  #pragma unroll
  for (int i = 0; i < 8; ++i)
    #pragma unroll
    for (int j = 0; j < 4; ++j) acc[i][j] = (f32x4){0.f, 0.f, 0.f, 0.f};

  // ---- staging helpers (2 x gload_lds16 each; dest wave-uniform base) ----
  auto stageA = [&](int buf, int h, int kk) {
    #pragma unroll
    for (int q = 0; q < 2; ++q) {
      int gr = m0 + h * 64 + q * 128 + rowT;
      gr = gr > MAXROWS - 1 ? MAXROWS - 1 : gr;
      gload_lds16(A + (size_t)gr * DDIM + kk + csE,
                  &As[buf][(h * 64 + q * 128 + w * 8) * 64]);
    }
  };
  auto stageB = [&](int buf, int h, int kk) {
    #pragma unroll
    for (int q = 0; q < 2; ++q) {
      const int row = h * 32 + (q * 2 + (rowT >> 5)) * 64 + (rowT & 31);
      const int rbase = h * 32 + (q * 2 + (w >> 2)) * 64 + (w & 3) * 8;
      gload_lds16(Bp + (size_t)(n0 + row) * DDIM + kk + csE,
                  &Bs[buf][rbase * 64]);
    }
  };

  // ---- prologue: stage tiles 0 and 1 fully; drain tile 0; publish ----
  stageA(0, 0, 0);  stageB(0, 0, 0);  stageB(0, 1, 0);  stageA(0, 1, 0);
  stageA(1, 0, 64); stageB(1, 0, 64); stageB(1, 1, 64); stageA(1, 1, 64);
  asm volatile("s_waitcnt vmcnt(8)" ::: "memory");
  asm volatile("s_barrier" ::: "memory");

  #define QUAD(MB, NB)                                                          \
    __builtin_amdgcn_s_setprio(1);                                              \
    _Pragma("unroll")                                                           \
    for (int mf = 0; mf < 4; ++mf)                                              \
      _Pragma("unroll")                                                         \
      for (int nf = 0; nf < 2; ++nf)                                            \
        _Pragma("unroll")                                                       \
        for (int ks = 0; ks < 2; ++ks)                                          \
          acc[(MB) + mf][(NB) + nf] = __builtin_amdgcn_mfma_f32_16x16x32_bf16(  \
              a[mf][ks], b[(NB) + nf][ks], acc[(MB) + mf][(NB) + nf], 0, 0, 0); \
    __builtin_amdgcn_s_setprio(0);

  constexpr int KT = DDIM / 64;   // 32
  for (int t = 0; t < KT; ++t) {
    const int cur = t & 1;
    const int kk2 = (t + 2) * 64;
    const bool st = (t + 2) < KT;
    const unsigned short* Ac = As[cur];
    const unsigned short* Bc = Bs[cur];
    bf16x8 a[4][2], b[4][2];

    // ---- P1: read Ah0 + Bh0; quad(h0, nf0-1) ----
    #pragma unroll
    for (int mf = 0; mf < 4; ++mf) {
      const int r = wm * 128 + mf * 16 + lr;
      #pragma unroll
      for (int ks = 0; ks < 2; ++ks)
        a[mf][ks] = *(const bf16x8*)(Ac + r * 64 + (((ks * 4 + kc) ^ (r & 7)) << 3));
    }
    #pragma unroll
    for (int nf = 0; nf < 2; ++nf) {
      const int r = wn * 64 + nf * 16 + lr;
      #pragma unroll
      for (int ks = 0; ks < 2; ++ks)
        b[nf][ks] = *(const bf16x8*)(Bc + r * 64 + (((ks * 4 + kc) ^ (r & 7)) << 3));
    }
    asm volatile("s_barrier" ::: "memory");
    QUAD(0, 0)
    asm volatile("s_barrier" ::: "memory");

    // ---- P2: read Bh1; stage Ah0(t+2); quad(h0, nf2-3) ----
    #pragma unroll
    for (int nf = 2; nf < 4; ++nf) {
      const int r = wn * 64 + nf * 16 + lr;
      #pragma unroll
      for (int ks = 0; ks < 2; ++ks)
        b[nf][ks] = *(const bf16x8*)(Bc + r * 64 + (((ks * 4 + kc) ^ (r & 7)) << 3));
    }
    if (st) stageA(cur, 0, kk2);
    asm volatile("s_barrier" ::: "memory");
    QUAD(0, 2)
    asm volatile("s_barrier" ::: "memory");

    // ---- P3: read Ah1; stage Bh0(t+2); quad(h1, nf0-1) ----
    #pragma unroll
    for (int mf = 0; mf < 4; ++mf) {
      const int r = wm * 128 + (mf + 4) * 16 + lr;
      #pragma unroll
      for (int ks = 0; ks < 2; ++ks)
        a[mf][ks] = *(const bf16x8*)(Ac + r * 64 + (((ks * 4 + kc) ^ (r & 7)) << 3));
    }
    if (st) stageB(cur, 0, kk2);
    asm volatile("s_barrier" ::: "memory");
    QUAD(4, 0)
    asm volatile("s_barrier" ::: "memory");

    // ---- P4: stage Bh1,Ah1(t+2); single counted wait; quad(h1, nf2-3) ----
    if (st) { stageB(cur, 1, kk2); stageA(cur, 1, kk2); }
    asm volatile("s_waitcnt vmcnt(8)" ::: "memory");
    asm volatile("s_barrier" ::: "memory");
    QUAD(4, 2)
    asm volatile("s_barrier" ::: "memory");
  }
  #undef QUAD

  // ---- epilogue: silu(even)*odd -> hid bf16; mask rows beyond segment ----
  const int fcol0 = (n0 >> 1) + wn * 32;
  #pragma unroll
  for (int mf = 0; mf < 8; ++mf) {
    const int row = m0 + wm * 128 + mf * 16 + (kc << 2);
    #pragma unroll
    for (int nf = 0; nf < 4; ++nf) {
      #pragma unroll
      for (int rr = 0; rr < 4; ++rr) {
        const float v = acc[mf][nf][rr];
        const float o = __shfl_xor(v, 1, 64);
        const float h = (l & 1) ? o : v;
        const float g = (l & 1) ? v : o;
        const float res = (h / (1.f + __expf(-h))) * g;
        const float vc = __shfl(res, (l & 48) | ((l & 7) << 1), 64);
        if (lr < 8 && row + rr < mend)
          hid[(size_t)(row + rr) * FDIM + fcol0 + nf * 8 + (l & 7)] = f2b(vc);
      }
    }
  }
}

// ---------------- GEMM2: 128x128 tile, 2-barrier (unchanged, proven) ----------------
__global__ void moe_gemm2(const unsigned short* __restrict__ A,
                          const unsigned short* __restrict__ B,
                          const int* __restrict__ base,
                          const int* __restrict__ rtok, const float* __restrict__ rgw,
                          float* __restrict__ out) {
  constexpr int KDIM = FDIM;      // 4096
  constexpr int NDIM = DDIM;      // 2048

  const int nwg = gridDim.x;
  const int q8 = nwg >> 3;
  const int bid = blockIdx.x;
  const int swz = (bid & 7) * q8 + (bid >> 3);
  const int mt = swz % MAXMT;
  const int ntl = swz / MAXMT;

  const int m0 = mt * 128;
  if (m0 >= base[8]) return;
  int e = 0;
  #pragma unroll
  for (int qq = 1; qq < 8; ++qq) if (m0 >= base[qq]) e = qq;
  const int n0 = ntl * 128;
  const unsigned short* Bp = B + (size_t)e * NDIM * KDIM;

  __shared__ __align__(16) unsigned short As[128 * 64];
  __shared__ __align__(16) unsigned short Bs[128 * 64];

  const int tid = threadIdx.x;
  const int l = tid & 63;
  const int w = tid >> 6;
  const int wm = w >> 1, wn = w & 1;
  const int lr = l & 15, kc = l >> 4;

  const f32x4 vzero = {0.f, 0.f, 0.f, 0.f};
  f32x4 acc[4][4];
  #pragma unroll
  for (int i = 0; i < 4; ++i)
    #pragma unroll
    for (int j = 0; j < 4; ++j) acc[i][j] = vzero;

  const int srow = w * 32 + (l >> 3);
  const int sc = l & 7;
  const unsigned short* Arow = A + (size_t)(m0 + srow) * KDIM;
  const unsigned short* Brow = Bp + (size_t)(n0 + srow) * KDIM;

  for (int k0 = 0; k0 < KDIM; k0 += 64) {
    #pragma unroll
    for (int qq = 0; qq < 4; ++qq) {
      const int r = srow + qq * 8;
      const int cg = (sc ^ (r & 7)) << 3;
      gload_lds16(Arow + (size_t)qq * 8 * KDIM + k0 + cg,
                  (unsigned short*)As + w * 2048 + qq * 512);
      gload_lds16(Brow + (size_t)qq * 8 * KDIM + k0 + cg,
                  (unsigned short*)Bs + w * 2048 + qq * 512);
    }
    __syncthreads();
    #pragma unroll
    for (int ks = 0; ks < 2; ++ks) {
      bf16x8 af[4], bfr[4];
      #pragma unroll
      for (int mf = 0; mf < 4; ++mf) {
        const int r = wm * 64 + mf * 16 + lr;
        const int c = (ks * 4 + kc) ^ (r & 7);
        af[mf] = *(const bf16x8*)((const char*)As + r * 128 + c * 16);
      }
      #pragma unroll
      for (int nf = 0; nf < 4; ++nf) {
        const int n = wn * 64 + nf * 16 + lr;
        const int c = (ks * 4 + kc) ^ (n & 7);
        bfr[nf] = *(const bf16x8*)((const char*)Bs + n * 128 + c * 16);
      }
      #pragma unroll
      for (int mf = 0; mf < 4; ++mf)
        #pragma unroll
        for (int nf = 0; nf < 4; ++nf)
          acc[mf][nf] = __builtin_amdgcn_mfma_f32_16x16x32_bf16(af[mf], bfr[nf], acc[mf][nf], 0, 0, 0);
    }
    __syncthreads();
  }
  #pragma unroll
  for (int mf = 0; mf < 4; ++mf) {
    const int row = m0 + wm * 64 + mf * 16 + (kc << 2);
    #pragma unroll
    for (int rr = 0; rr < 4; ++rr) {
      const int tok = rtok[row + rr];
      if (tok < 0) continue;
      const float gwt = rgw[row + rr];
      float* orow = out + (size_t)tok * DDIM;
      #pragma unroll
      for (int nf = 0; nf < 4; ++nf) {
        const int col = n0 + wn * 64 + nf * 16 + lr;
        atomicAdd(orow + col, gwt * acc[mf][nf][rr]);
      }
    }
  }
}

// ---------------- launch ----------------
// ws layout (bytes)
#define OFF_CNT   0u
#define OFF_BASE  64u
#define OFF_TE    128u          // 40 ints
#define OFF_TM0   512u
#define OFF_TEND  896u
#define OFF_SELE  4096u
#define OFF_SELW  36864u
#define OFF_RTOK  69632u
#define OFF_RGW   106496u
#define OFF_XC    1048576u      // 9216*2048 bf16 = 37748736
#define OFF_HID   38797312u     // 9216*4096 bf16 = 75497472
#define OFF_WBUF  114294784u    // 8*8192*2048 bf16 = 268435456 -> end ~365 MB

extern "C" void kernel_launch(void* const* d_in, const int* in_sizes, int n_in,
                              void* d_out, int out_size, void* d_ws, size_t ws_size,
                              hipStream_t stream) {
  const float* x  = (const float*)d_in[0];
  const float* gw = (const float*)d_in[1];
  const float* w1 = (const float*)d_in[2];
  const float* w3 = (const float*)d_in[3];
  const float* w2 = (const float*)d_in[4];
  float* out = (float*)d_out;
  char* ws = (char*)d_ws;

  int*   cnt   = (int*)(ws + OFF_CNT);
  int*   base  = (int*)(ws + OFF_BASE);
  int*   tE    = (int*)(ws + OFF_TE);
  int*   tM0   = (int*)(ws + OFF_TM0);
  int*   tEnd  = (int*)(ws + OFF_TEND);
  int*   sel_e = (int*)(ws + OFF_SELE);
  float* sel_w = (float*)(ws + OFF_SELW);
  int*   rtok  = (int*)(ws + OFF_RTOK);
  float* rgw   = (float*)(ws + OFF_RGW);
  unsigned short* xc   = (unsigned short*)(ws + OFF_XC);
  unsigned short* hid  = (unsigned short*)(ws + OFF_HID);
  unsigned short* wbuf = (unsigned short*)(ws + OFF_WBUF);

  hipMemsetAsync(d_out, 0, (size_t)T_TOK * DDIM * sizeof(float), stream);
  gate_topk<<<T_TOK / 4, 256, 0, stream>>>(x, gw, sel_e, sel_w);
  build_lists<<<1, 256, 0, stream>>>(sel_e, sel_w, cnt, base, rtok, rgw, tE, tM0, tEnd);
  gather_x<<<MAXROWS, 256, 0, stream>>>(x, base, rtok, xc);
  // w13t[e][8192][2048]: even rows = w1 cols, odd rows = w3 cols
  conv_t<<<dim3(32, 64, 8), 256, 0, stream>>>(w1, wbuf, DDIM, FDIM, 2, 0);
  conv_t<<<dim3(32, 64, 8), 256, 0, stream>>>(w3, wbuf, DDIM, FDIM, 2, 1);
  // gemm1: 40 m-tiles x 32 n-tiles = 1280 blocks (%8==0)
  moe_gemm1<<<NT256 * 32, 512, 0, stream>>>(xc, wbuf, tE, tM0, tEnd, hid);
  // reuse wbuf for w2t[e][2048][4096]
  conv_t<<<dim3(64, 32, 8), 256, 0, stream>>>(w2, wbuf, FDIM, DDIM, 1, 0);
  moe_gemm2<<<MAXMT * 16, 256, 0, stream>>>(hid, wbuf, base, rtok, rgw, out);
}

// Round 7
// 937.182 us; speedup vs baseline: 1.0354x; 1.0354x over previous
//
#include <hip/hip_runtime.h>
#include <hip/hip_bf16.h>

#define T_TOK 4096
#define DDIM  2048
#define FDIM  4096
#define NEXP  8
#define MAXROWS 9216   // T*2 + 8*128 padding
#define MAXMT   72     // MAXROWS/128

typedef __attribute__((ext_vector_type(4))) float f32x4;
typedef __attribute__((ext_vector_type(8))) short bf16x8;

__device__ __forceinline__ unsigned short f2b(float f) {
  union { float f; unsigned u; } c; c.f = f;
  unsigned r = c.u + 0x7FFFu + ((c.u >> 16) & 1u);
  return (unsigned short)(r >> 16);
}

// async global->LDS, 16B per lane; LDS dest must be wave-uniform base (+lane*16 implicit)
__device__ __forceinline__ void gload_lds16(const void* g, void* l) {
  __builtin_amdgcn_global_load_lds((__attribute__((address_space(1))) void*)(g),
                                   (__attribute__((address_space(3))) void*)(l),
                                   16, 0, 0);
}

// ---------------- gating: one wave per token ----------------
__global__ void gate_topk(const float* __restrict__ x, const float* __restrict__ gw,
                          int* __restrict__ sel_e, float* __restrict__ sel_w) {
  const int t = blockIdx.x * 4 + (threadIdx.x >> 6);
  const int l = threadIdx.x & 63;
  const float* xr = x + (size_t)t * DDIM;
  float acc[8];
  #pragma unroll
  for (int e = 0; e < 8; ++e) acc[e] = 0.f;
  for (int d = l; d < DDIM; d += 64) {
    const float xv = xr[d];
    const float* g = gw + d * 8;
    #pragma unroll
    for (int e = 0; e < 8; ++e) acc[e] = fmaf(xv, g[e], acc[e]);
  }
  #pragma unroll
  for (int e = 0; e < 8; ++e) {
    float v = acc[e];
    #pragma unroll
    for (int off = 32; off; off >>= 1) v += __shfl_xor(v, off, 64);
    acc[e] = v;
  }
  if (l == 0) {
    int e0 = 0; float v0 = acc[0];
    #pragma unroll
    for (int e = 1; e < 8; ++e) if (acc[e] > v0) { v0 = acc[e]; e0 = e; }
    int e1 = -1; float v1 = -1e30f;
    #pragma unroll
    for (int e = 0; e < 8; ++e) if (e != e0 && acc[e] > v1) { v1 = acc[e]; e1 = e; }
    const float ex = __expf(v1 - v0);
    const float w0 = 1.f / (1.f + ex);
    sel_e[t * 2] = e0; sel_e[t * 2 + 1] = e1;
    sel_w[t * 2] = w0; sel_w[t * 2 + 1] = ex * w0;
  }
}

// ---------------- per-expert lists (single block) ----------------
__global__ void build_lists(const int* __restrict__ sel_e, const float* __restrict__ sel_w,
                            int* __restrict__ cnt, int* __restrict__ base,
                            int* __restrict__ row_token, float* __restrict__ row_gw,
                            int* __restrict__ trow) {
  __shared__ int c[8], f[8], b[9];
  const int tid = threadIdx.x;
  if (tid < 8) { c[tid] = 0; f[tid] = 0; }
  __syncthreads();
  for (int t = tid; t < T_TOK; t += 256) {
    atomicAdd(&c[sel_e[t * 2]], 1);
    atomicAdd(&c[sel_e[t * 2 + 1]], 1);
  }
  __syncthreads();
  if (tid == 0) {
    int r = 0;
    for (int e = 0; e < 8; ++e) { b[e] = r; r += ((c[e] + 127) >> 7) << 7; }
    b[8] = r;
    for (int e = 0; e < 8; ++e) { cnt[e] = c[e]; base[e] = b[e]; }
    base[8] = r;
  }
  __syncthreads();
  for (int i = tid; i < MAXROWS; i += 256) { row_token[i] = -1; row_gw[i] = 0.f; }
  __syncthreads();
  for (int t = tid; t < T_TOK; t += 256) {
    #pragma unroll
    for (int k = 0; k < 2; ++k) {
      const int e = sel_e[t * 2 + k];
      const int p = b[e] + atomicAdd(&f[e], 1);
      row_token[p] = t; row_gw[p] = sel_w[t * 2 + k];
      trow[t * 2 + k] = p;                       // inverse map for combine
    }
  }
}

// ---------------- gather x rows -> compact bf16 ----------------
__global__ void gather_x(const float* __restrict__ x, const int* __restrict__ base,
                         const int* __restrict__ row_token, unsigned short* __restrict__ xc) {
  const int i = blockIdx.x;
  if (i >= base[8]) return;
  const int t = row_token[i];
  const int tid = threadIdx.x;
  union { uint4 u; unsigned short s[8]; } o;
  if (t < 0) { o.u.x = 0u; o.u.y = 0u; o.u.z = 0u; o.u.w = 0u; }
  else {
    const float4* src = (const float4*)(x + (size_t)t * DDIM + tid * 8);
    const float4 a = src[0], bb = src[1];
    o.s[0] = f2b(a.x);  o.s[1] = f2b(a.y);  o.s[2] = f2b(a.z);  o.s[3] = f2b(a.w);
    o.s[4] = f2b(bb.x); o.s[5] = f2b(bb.y); o.s[6] = f2b(bb.z); o.s[7] = f2b(bb.w);
  }
  ((uint4*)(xc + (size_t)i * DDIM))[tid] = o.u;
}

// ---------------- transpose + fp32->bf16 convert ----------------
__global__ void conv_t(const float* __restrict__ src, unsigned short* __restrict__ dst,
                       int R, int C, int rowMul, int rowAdd) {
  const int e = blockIdx.z;
  const int r0 = blockIdx.x * 64, c0 = blockIdx.y * 64;
  const float* s = src + (size_t)e * R * C + (size_t)r0 * C + c0;
  unsigned short* d = dst + (size_t)e * R * C * rowMul;
  __shared__ unsigned short T[64][68];
  const int t = threadIdx.x;
  {
    const int i = t >> 2, jb = (t & 3) * 16;
    #pragma unroll
    for (int k2 = 0; k2 < 4; ++k2) {
      const float4 v = *(const float4*)(s + (size_t)i * C + jb + k2 * 4);
      uint2 uu;
      uu.x = (unsigned)f2b(v.x) | ((unsigned)f2b(v.y) << 16);
      uu.y = (unsigned)f2b(v.z) | ((unsigned)f2b(v.w) << 16);
      *(uint2*)&T[i][jb + k2 * 4] = uu;
    }
  }
  __syncthreads();
  {
    const int j = t >> 2, ib = (t & 3) * 16;
    union { uint4 q[2]; unsigned short s16[16]; } pk;
    #pragma unroll
    for (int i = 0; i < 16; ++i) pk.s16[i] = T[ib + i][j];
    unsigned short* drow = d + (size_t)(rowMul * (c0 + j) + rowAdd) * R + r0 + ib;
    *(uint4*)drow = pk.q[0];
    *(uint4*)(drow + 8) = pk.q[1];
  }
}

// ---------------- GEMM1: 128x128 tile, BK=64, 4 waves, 2-barrier (r3-proven) --------
// hidden = silu(xc@w1[e]) * (xc@w3[e]); B = w13t[e][8192][2048] (even rows w1, odd w3)
__global__ void moe_gemm1(const unsigned short* __restrict__ A,
                          const unsigned short* __restrict__ B,
                          const int* __restrict__ base,
                          unsigned short* __restrict__ hid) {
  constexpr int KDIM = DDIM;      // 2048
  constexpr int NDIM = 2 * FDIM;  // 8192

  const int nwg = gridDim.x;
  const int q8 = nwg >> 3;
  const int bid = blockIdx.x;
  const int swz = (bid & 7) * q8 + (bid >> 3);
  const int mt = swz % MAXMT;        // m-fast: consecutive swz share the B-panel
  const int nt = swz / MAXMT;

  const int m0 = mt * 128;
  if (m0 >= base[8]) return;
  int e = 0;
  #pragma unroll
  for (int qq = 1; qq < 8; ++qq) if (m0 >= base[qq]) e = qq;
  const int n0 = nt * 128;
  const unsigned short* Bp = B + (size_t)e * NDIM * KDIM;

  __shared__ __align__(16) unsigned short As[128 * 64];
  __shared__ __align__(16) unsigned short Bs[128 * 64];

  const int tid = threadIdx.x;
  const int l = tid & 63;
  const int w = tid >> 6;
  const int wm = w >> 1, wn = w & 1;
  const int lr = l & 15, kc = l >> 4;

  const f32x4 vzero = {0.f, 0.f, 0.f, 0.f};
  f32x4 acc[4][4];
  #pragma unroll
  for (int i = 0; i < 4; ++i)
    #pragma unroll
    for (int j = 0; j < 4; ++j) acc[i][j] = vzero;

  const int srow = w * 32 + (l >> 3);
  const int sc = l & 7;
  const unsigned short* Arow = A + (size_t)(m0 + srow) * KDIM;
  const unsigned short* Brow = Bp + (size_t)(n0 + srow) * KDIM;

  for (int k0 = 0; k0 < KDIM; k0 += 64) {
    #pragma unroll
    for (int qq = 0; qq < 4; ++qq) {
      const int r = srow + qq * 8;
      const int cg = (sc ^ (r & 7)) << 3;
      gload_lds16(Arow + (size_t)qq * 8 * KDIM + k0 + cg,
                  (unsigned short*)As + w * 2048 + qq * 512);
      gload_lds16(Brow + (size_t)qq * 8 * KDIM + k0 + cg,
                  (unsigned short*)Bs + w * 2048 + qq * 512);
    }
    __syncthreads();
    #pragma unroll
    for (int ks = 0; ks < 2; ++ks) {
      bf16x8 af[4], bfr[4];
      #pragma unroll
      for (int mf = 0; mf < 4; ++mf) {
        const int r = wm * 64 + mf * 16 + lr;
        const int c = (ks * 4 + kc) ^ (r & 7);
        af[mf] = *(const bf16x8*)((const char*)As + r * 128 + c * 16);
      }
      #pragma unroll
      for (int nf = 0; nf < 4; ++nf) {
        const int n = wn * 64 + nf * 16 + lr;
        const int c = (ks * 4 + kc) ^ (n & 7);
        bfr[nf] = *(const bf16x8*)((const char*)Bs + n * 128 + c * 16);
      }
      #pragma unroll
      for (int mf = 0; mf < 4; ++mf)
        #pragma unroll
        for (int nf = 0; nf < 4; ++nf)
          acc[mf][nf] = __builtin_amdgcn_mfma_f32_16x16x32_bf16(af[mf], bfr[nf], acc[mf][nf], 0, 0, 0);
    }
    __syncthreads();
  }

  // epilogue: cols interleaved even=h(w1), odd=g(w3); out col = global_col/2
  const int fbase = (n0 >> 1) + wn * 32;
  #pragma unroll
  for (int mf = 0; mf < 4; ++mf) {
    const int row = m0 + wm * 64 + mf * 16 + (kc << 2);
    #pragma unroll
    for (int nf = 0; nf < 4; ++nf)
      #pragma unroll
      for (int rr = 0; rr < 4; ++rr) {
        const float v = acc[mf][nf][rr];
        const float o = __shfl_xor(v, 1, 64);
        const float h = (l & 1) ? o : v;
        const float g = (l & 1) ? v : o;
        const float res = (h / (1.f + __expf(-h))) * g;
        const float vc = __shfl(res, (l & 48) | ((l & 7) << 1), 64);
        if (lr < 8)
          hid[(size_t)(row + rr) * FDIM + fbase + nf * 8 + (l & 7)] = f2b(vc);
      }
  }
}

// ---------------- GEMM2: 128x128 tile, 2-barrier; dense bf16 eo stores (no atomics) --
__global__ void moe_gemm2(const unsigned short* __restrict__ A,
                          const unsigned short* __restrict__ B,
                          const int* __restrict__ base,
                          unsigned short* __restrict__ eo) {
  constexpr int KDIM = FDIM;      // 4096
  constexpr int NDIM = DDIM;      // 2048

  const int nwg = gridDim.x;
  const int q8 = nwg >> 3;
  const int bid = blockIdx.x;
  const int swz = (bid & 7) * q8 + (bid >> 3);
  const int mt = swz % MAXMT;
  const int ntl = swz / MAXMT;

  const int m0 = mt * 128;
  if (m0 >= base[8]) return;
  int e = 0;
  #pragma unroll
  for (int qq = 1; qq < 8; ++qq) if (m0 >= base[qq]) e = qq;
  const int n0 = ntl * 128;
  const unsigned short* Bp = B + (size_t)e * NDIM * KDIM;

  __shared__ __align__(16) unsigned short As[128 * 64];
  __shared__ __align__(16) unsigned short Bs[128 * 64];

  const int tid = threadIdx.x;
  const int l = tid & 63;
  const int w = tid >> 6;
  const int wm = w >> 1, wn = w & 1;
  const int lr = l & 15, kc = l >> 4;

  const f32x4 vzero = {0.f, 0.f, 0.f, 0.f};
  f32x4 acc[4][4];
  #pragma unroll
  for (int i = 0; i < 4; ++i)
    #pragma unroll
    for (int j = 0; j < 4; ++j) acc[i][j] = vzero;

  const int srow = w * 32 + (l >> 3);
  const int sc = l & 7;
  const unsigned short* Arow = A + (size_t)(m0 + srow) * KDIM;
  const unsigned short* Brow = Bp + (size_t)(n0 + srow) * KDIM;

  for (int k0 = 0; k0 < KDIM; k0 += 64) {
    #pragma unroll
    for (int qq = 0; qq < 4; ++qq) {
      const int r = srow + qq * 8;
      const int cg = (sc ^ (r & 7)) << 3;
      gload_lds16(Arow + (size_t)qq * 8 * KDIM + k0 + cg,
                  (unsigned short*)As + w * 2048 + qq * 512);
      gload_lds16(Brow + (size_t)qq * 8 * KDIM + k0 + cg,
                  (unsigned short*)Bs + w * 2048 + qq * 512);
    }
    __syncthreads();
    #pragma unroll
    for (int ks = 0; ks < 2; ++ks) {
      bf16x8 af[4], bfr[4];
      #pragma unroll
      for (int mf = 0; mf < 4; ++mf) {
        const int r = wm * 64 + mf * 16 + lr;
        const int c = (ks * 4 + kc) ^ (r & 7);
        af[mf] = *(const bf16x8*)((const char*)As + r * 128 + c * 16);
      }
      #pragma unroll
      for (int nf = 0; nf < 4; ++nf) {
        const int n = wn * 64 + nf * 16 + lr;
        const int c = (ks * 4 + kc) ^ (n & 7);
        bfr[nf] = *(const bf16x8*)((const char*)Bs + n * 128 + c * 16);
      }
      #pragma unroll
      for (int mf = 0; mf < 4; ++mf)
        #pragma unroll
        for (int nf = 0; nf < 4; ++nf)
          acc[mf][nf] = __builtin_amdgcn_mfma_f32_16x16x32_bf16(af[mf], bfr[nf], acc[mf][nf], 0, 0, 0);
    }
    __syncthreads();
  }
  // epilogue: plain bf16 stores (token combine happens in a separate kernel)
  #pragma unroll
  for (int mf = 0; mf < 4; ++mf) {
    const int row = m0 + wm * 64 + mf * 16 + (kc << 2);
    #pragma unroll
    for (int rr = 0; rr < 4; ++rr) {
      unsigned short* erow = eo + (size_t)(row + rr) * DDIM;
      #pragma unroll
      for (int nf = 0; nf < 4; ++nf) {
        const int col = n0 + wn * 64 + nf * 16 + lr;
        erow[col] = f2b(acc[mf][nf][rr]);
      }
    }
  }
}

// ---------------- combine: out[t] = w0*eo[row0] + w1*eo[row1] ----------------
__global__ void combine_k(const unsigned short* __restrict__ eo,
                          const int* __restrict__ trow, const float* __restrict__ sel_w,
                          float* __restrict__ out) {
  const int t = blockIdx.x;
  const int r0 = trow[t * 2], r1 = trow[t * 2 + 1];
  const float w0 = sel_w[t * 2], w1 = sel_w[t * 2 + 1];
  const int c = threadIdx.x * 8;
  union { uint4 u; unsigned short s[8]; } a, b;
  a.u = *(const uint4*)(eo + (size_t)r0 * DDIM + c);
  b.u = *(const uint4*)(eo + (size_t)r1 * DDIM + c);
  float o[8];
  #pragma unroll
  for (int j = 0; j < 8; ++j) {
    union { unsigned u; float f; } fa, fb;
    fa.u = (unsigned)a.s[j] << 16;
    fb.u = (unsigned)b.s[j] << 16;
    o[j] = w0 * fa.f + w1 * fb.f;
  }
  float4* dst = (float4*)(out + (size_t)t * DDIM + c);
  dst[0] = make_float4(o[0], o[1], o[2], o[3]);
  dst[1] = make_float4(o[4], o[5], o[6], o[7]);
}

// ---------------- launch ----------------
// ws layout (bytes)
#define OFF_CNT   0u
#define OFF_BASE  64u
#define OFF_SELE  4096u
#define OFF_SELW  36864u
#define OFF_RTOK  69632u
#define OFF_RGW   106496u
#define OFF_TROW  143360u       // 4096*2 int = 32768 -> 176128
#define OFF_XC    1048576u      // 9216*2048 bf16 = 37748736 (eo aliases this after gemm1)
#define OFF_HID   38797312u     // 9216*4096 bf16 = 75497472
#define OFF_WBUF  114294784u    // 8*8192*2048 bf16 = 268435456 -> end ~365 MB

extern "C" void kernel_launch(void* const* d_in, const int* in_sizes, int n_in,
                              void* d_out, int out_size, void* d_ws, size_t ws_size,
                              hipStream_t stream) {
  const float* x  = (const float*)d_in[0];
  const float* gw = (const float*)d_in[1];
  const float* w1 = (const float*)d_in[2];
  const float* w3 = (const float*)d_in[3];
  const float* w2 = (const float*)d_in[4];
  float* out = (float*)d_out;
  char* ws = (char*)d_ws;

  int*   cnt   = (int*)(ws + OFF_CNT);
  int*   base  = (int*)(ws + OFF_BASE);
  int*   sel_e = (int*)(ws + OFF_SELE);
  float* sel_w = (float*)(ws + OFF_SELW);
  int*   rtok  = (int*)(ws + OFF_RTOK);
  float* rgw   = (float*)(ws + OFF_RGW);
  int*   trow  = (int*)(ws + OFF_TROW);
  unsigned short* xc   = (unsigned short*)(ws + OFF_XC);
  unsigned short* hid  = (unsigned short*)(ws + OFF_HID);
  unsigned short* wbuf = (unsigned short*)(ws + OFF_WBUF);
  unsigned short* eo   = xc;   // xc is dead after gemm1; reuse for expert outputs

  gate_topk<<<T_TOK / 4, 256, 0, stream>>>(x, gw, sel_e, sel_w);
  build_lists<<<1, 256, 0, stream>>>(sel_e, sel_w, cnt, base, rtok, rgw, trow);
  gather_x<<<MAXROWS, 256, 0, stream>>>(x, base, rtok, xc);
  // w13t[e][8192][2048]: even rows = w1 cols, odd rows = w3 cols
  conv_t<<<dim3(32, 64, 8), 256, 0, stream>>>(w1, wbuf, DDIM, FDIM, 2, 0);
  conv_t<<<dim3(32, 64, 8), 256, 0, stream>>>(w3, wbuf, DDIM, FDIM, 2, 1);
  // gemm1: 72*64 = 4608 blocks (%8==0)
  moe_gemm1<<<MAXMT * 64, 256, 0, stream>>>(xc, wbuf, base, hid);
  // reuse wbuf for w2t[e][2048][4096]
  conv_t<<<dim3(64, 32, 8), 256, 0, stream>>>(w2, wbuf, FDIM, DDIM, 1, 0);
  // gemm2: 72*16 = 1152 blocks (%8==0), writes dense eo (no atomics)
  moe_gemm2<<<MAXMT * 16, 256, 0, stream>>>(hid, wbuf, base, eo);
  combine_k<<<T_TOK, 256, 0, stream>>>(eo, trow, sel_w, out);
}

// Round 8
// 785.801 us; speedup vs baseline: 1.2349x; 1.1926x over previous
//
#include <hip/hip_runtime.h>
#include <hip/hip_bf16.h>

#define T_TOK 4096
#define DDIM  2048
#define FDIM  4096
#define NEXP  8
#define MAXROWS 9216   // T*2 + 8*128 padding
#define MAXMT   72     // MAXROWS/128

typedef __attribute__((ext_vector_type(4))) float f32x4;
typedef __attribute__((ext_vector_type(8))) short bf16x8;

__device__ __forceinline__ unsigned short f2b(float f) {
  union { float f; unsigned u; } c; c.f = f;
  unsigned r = c.u + 0x7FFFu + ((c.u >> 16) & 1u);
  return (unsigned short)(r >> 16);
}

// async global->LDS, 16B per lane; LDS dest must be wave-uniform base (+lane*16 implicit)
__device__ __forceinline__ void gload_lds16(const void* g, void* l) {
  __builtin_amdgcn_global_load_lds((__attribute__((address_space(1))) void*)(g),
                                   (__attribute__((address_space(3))) void*)(l),
                                   16, 0, 0);
}

// 2D-chunked XCD block mapping: XCD x owns m-tiles [x*MT_PER, +MT_PER), sweeps n
// in groups of 4. B-panel reuse distance = 4 blocks (2 MB, L2-hot); A-chunk
// (MT_PER tiles) L2/L3-resident per XCD; B streamed ~once per owning XCD.
__device__ __forceinline__ void xcd_map2d(int bid, int MT_PER, int NT, int& mt, int& nt) {
  const int xcd = bid & 7;
  const int li = bid >> 3;                 // 0 .. MT_PER*NT-1
  const int grp = MT_PER * 4;              // blocks per (m-chunk x 4-n) super-tile
  const int ng = li / grp;
  const int rem = li % grp;
  mt = xcd * MT_PER + (rem >> 2);
  nt = ng * 4 + (rem & 3);
}

// ---------------- gating: one wave per token ----------------
__global__ void gate_topk(const float* __restrict__ x, const float* __restrict__ gw,
                          int* __restrict__ sel_e, float* __restrict__ sel_w) {
  const int t = blockIdx.x * 4 + (threadIdx.x >> 6);
  const int l = threadIdx.x & 63;
  const float* xr = x + (size_t)t * DDIM;
  float acc[8];
  #pragma unroll
  for (int e = 0; e < 8; ++e) acc[e] = 0.f;
  for (int d = l; d < DDIM; d += 64) {
    const float xv = xr[d];
    const float* g = gw + d * 8;
    #pragma unroll
    for (int e = 0; e < 8; ++e) acc[e] = fmaf(xv, g[e], acc[e]);
  }
  #pragma unroll
  for (int e = 0; e < 8; ++e) {
    float v = acc[e];
    #pragma unroll
    for (int off = 32; off; off >>= 1) v += __shfl_xor(v, off, 64);
    acc[e] = v;
  }
  if (l == 0) {
    int e0 = 0; float v0 = acc[0];
    #pragma unroll
    for (int e = 1; e < 8; ++e) if (acc[e] > v0) { v0 = acc[e]; e0 = e; }
    int e1 = -1; float v1 = -1e30f;
    #pragma unroll
    for (int e = 0; e < 8; ++e) if (e != e0 && acc[e] > v1) { v1 = acc[e]; e1 = e; }
    const float ex = __expf(v1 - v0);
    const float w0 = 1.f / (1.f + ex);
    sel_e[t * 2] = e0; sel_e[t * 2 + 1] = e1;
    sel_w[t * 2] = w0; sel_w[t * 2 + 1] = ex * w0;
  }
}

// ---------------- per-expert lists (single block) ----------------
__global__ void build_lists(const int* __restrict__ sel_e, const float* __restrict__ sel_w,
                            int* __restrict__ cnt, int* __restrict__ base,
                            int* __restrict__ row_token, float* __restrict__ row_gw,
                            int* __restrict__ trow) {
  __shared__ int c[8], f[8], b[9];
  const int tid = threadIdx.x;
  if (tid < 8) { c[tid] = 0; f[tid] = 0; }
  __syncthreads();
  for (int t = tid; t < T_TOK; t += 256) {
    atomicAdd(&c[sel_e[t * 2]], 1);
    atomicAdd(&c[sel_e[t * 2 + 1]], 1);
  }
  __syncthreads();
  if (tid == 0) {
    int r = 0;
    for (int e = 0; e < 8; ++e) { b[e] = r; r += ((c[e] + 127) >> 7) << 7; }
    b[8] = r;
    for (int e = 0; e < 8; ++e) { cnt[e] = c[e]; base[e] = b[e]; }
    base[8] = r;
  }
  __syncthreads();
  for (int i = tid; i < MAXROWS; i += 256) { row_token[i] = -1; row_gw[i] = 0.f; }
  __syncthreads();
  for (int t = tid; t < T_TOK; t += 256) {
    #pragma unroll
    for (int k = 0; k < 2; ++k) {
      const int e = sel_e[t * 2 + k];
      const int p = b[e] + atomicAdd(&f[e], 1);
      row_token[p] = t; row_gw[p] = sel_w[t * 2 + k];
      trow[t * 2 + k] = p;                       // inverse map for combine
    }
  }
}

// ---------------- gather x rows -> compact bf16 ----------------
__global__ void gather_x(const float* __restrict__ x, const int* __restrict__ base,
                         const int* __restrict__ row_token, unsigned short* __restrict__ xc) {
  const int i = blockIdx.x;
  if (i >= base[8]) return;
  const int t = row_token[i];
  const int tid = threadIdx.x;
  union { uint4 u; unsigned short s[8]; } o;
  if (t < 0) { o.u.x = 0u; o.u.y = 0u; o.u.z = 0u; o.u.w = 0u; }
  else {
    const float4* src = (const float4*)(x + (size_t)t * DDIM + tid * 8);
    const float4 a = src[0], bb = src[1];
    o.s[0] = f2b(a.x);  o.s[1] = f2b(a.y);  o.s[2] = f2b(a.z);  o.s[3] = f2b(a.w);
    o.s[4] = f2b(bb.x); o.s[5] = f2b(bb.y); o.s[6] = f2b(bb.z); o.s[7] = f2b(bb.w);
  }
  ((uint4*)(xc + (size_t)i * DDIM))[tid] = o.u;
}

// ---------------- transpose + fp32->bf16 convert ----------------
// Generic: src [e][R][C] fp32 -> dst per-expert [C*rowMul][R] bf16 (row=rowMul*c+rowAdd)
__device__ __forceinline__ void conv_tile(const float* s, unsigned short* d,
                                          int R, int C, int rowMul, int rowAdd,
                                          int r0, int c0, int tid) {
  __shared__ unsigned short T[64][68];
  {
    const int i = tid >> 2, jb = (tid & 3) * 16;
    #pragma unroll
    for (int k2 = 0; k2 < 4; ++k2) {
      const float4 v = *(const float4*)(s + (size_t)(r0 + i) * C + c0 + jb + k2 * 4);
      uint2 uu;
      uu.x = (unsigned)f2b(v.x) | ((unsigned)f2b(v.y) << 16);
      uu.y = (unsigned)f2b(v.z) | ((unsigned)f2b(v.w) << 16);
      *(uint2*)&T[i][jb + k2 * 4] = uu;
    }
  }
  __syncthreads();
  {
    const int j = tid >> 2, ib = (tid & 3) * 16;
    union { uint4 q[2]; unsigned short s16[16]; } pk;
    #pragma unroll
    for (int i = 0; i < 16; ++i) pk.s16[i] = T[ib + i][j];
    unsigned short* drow = d + (size_t)(rowMul * (c0 + j) + rowAdd) * R + r0 + ib;
    *(uint4*)drow = pk.q[0];
    *(uint4*)(drow + 8) = pk.q[1];
  }
}

// merged w1+w3 conversion: z<8 -> w1 (rowAdd 0), z>=8 -> w3 (rowAdd 1)
__global__ void conv_w13(const float* __restrict__ w1, const float* __restrict__ w3,
                         unsigned short* __restrict__ dst) {
  const int z = blockIdx.z;
  const int e = z & 7;
  const int isw3 = z >> 3;
  const float* s = (isw3 ? w3 : w1) + (size_t)e * DDIM * FDIM;
  unsigned short* d = dst + (size_t)e * DDIM * FDIM * 2;
  conv_tile(s, d, DDIM, FDIM, 2, isw3, blockIdx.x * 64, blockIdx.y * 64, threadIdx.x);
}

__global__ void conv_w2(const float* __restrict__ w2, unsigned short* __restrict__ dst) {
  const int e = blockIdx.z;
  const float* s = w2 + (size_t)e * FDIM * DDIM;
  unsigned short* d = dst + (size_t)e * FDIM * DDIM;
  conv_tile(s, d, FDIM, DDIM, 1, 0, blockIdx.x * 64, blockIdx.y * 64, threadIdx.x);
}

// ---------------- GEMM1: 128x128 tile, BK=64, 4 waves, 2-barrier (proven) -----------
// hidden = silu(xc@w1[e]) * (xc@w3[e]); B = w13t[e][8192][2048] (even rows w1, odd w3)
__global__ void moe_gemm1(const unsigned short* __restrict__ A,
                          const unsigned short* __restrict__ B,
                          const int* __restrict__ base,
                          unsigned short* __restrict__ hid) {
  constexpr int KDIM = DDIM;      // 2048
  constexpr int NDIM = 2 * FDIM;  // 8192

  int mt, nt;
  xcd_map2d(blockIdx.x, MAXMT / 8, NDIM / 128, mt, nt);

  const int m0 = mt * 128;
  if (m0 >= base[8]) return;
  int e = 0;
  #pragma unroll
  for (int qq = 1; qq < 8; ++qq) if (m0 >= base[qq]) e = qq;
  const int n0 = nt * 128;
  const unsigned short* Bp = B + (size_t)e * NDIM * KDIM;

  __shared__ __align__(16) unsigned short As[128 * 64];
  __shared__ __align__(16) unsigned short Bs[128 * 64];

  const int tid = threadIdx.x;
  const int l = tid & 63;
  const int w = tid >> 6;
  const int wm = w >> 1, wn = w & 1;
  const int lr = l & 15, kc = l >> 4;

  const f32x4 vzero = {0.f, 0.f, 0.f, 0.f};
  f32x4 acc[4][4];
  #pragma unroll
  for (int i = 0; i < 4; ++i)
    #pragma unroll
    for (int j = 0; j < 4; ++j) acc[i][j] = vzero;

  const int srow = w * 32 + (l >> 3);
  const int sc = l & 7;
  const unsigned short* Arow = A + (size_t)(m0 + srow) * KDIM;
  const unsigned short* Brow = Bp + (size_t)(n0 + srow) * KDIM;

  for (int k0 = 0; k0 < KDIM; k0 += 64) {
    #pragma unroll
    for (int qq = 0; qq < 4; ++qq) {
      const int r = srow + qq * 8;
      const int cg = (sc ^ (r & 7)) << 3;
      gload_lds16(Arow + (size_t)qq * 8 * KDIM + k0 + cg,
                  (unsigned short*)As + w * 2048 + qq * 512);
      gload_lds16(Brow + (size_t)qq * 8 * KDIM + k0 + cg,
                  (unsigned short*)Bs + w * 2048 + qq * 512);
    }
    __syncthreads();
    #pragma unroll
    for (int ks = 0; ks < 2; ++ks) {
      bf16x8 af[4], bfr[4];
      #pragma unroll
      for (int mf = 0; mf < 4; ++mf) {
        const int r = wm * 64 + mf * 16 + lr;
        const int c = (ks * 4 + kc) ^ (r & 7);
        af[mf] = *(const bf16x8*)((const char*)As + r * 128 + c * 16);
      }
      #pragma unroll
      for (int nf = 0; nf < 4; ++nf) {
        const int n = wn * 64 + nf * 16 + lr;
        const int c = (ks * 4 + kc) ^ (n & 7);
        bfr[nf] = *(const bf16x8*)((const char*)Bs + n * 128 + c * 16);
      }
      #pragma unroll
      for (int mf = 0; mf < 4; ++mf)
        #pragma unroll
        for (int nf = 0; nf < 4; ++nf)
          acc[mf][nf] = __builtin_amdgcn_mfma_f32_16x16x32_bf16(af[mf], bfr[nf], acc[mf][nf], 0, 0, 0);
    }
    __syncthreads();
  }

  // epilogue: cols interleaved even=h(w1), odd=g(w3); out col = global_col/2
  const int fbase = (n0 >> 1) + wn * 32;
  #pragma unroll
  for (int mf = 0; mf < 4; ++mf) {
    const int row = m0 + wm * 64 + mf * 16 + (kc << 2);
    #pragma unroll
    for (int nf = 0; nf < 4; ++nf)
      #pragma unroll
      for (int rr = 0; rr < 4; ++rr) {
        const float v = acc[mf][nf][rr];
        const float o = __shfl_xor(v, 1, 64);
        const float h = (l & 1) ? o : v;
        const float g = (l & 1) ? v : o;
        const float res = (h / (1.f + __expf(-h))) * g;
        const float vc = __shfl(res, (l & 48) | ((l & 7) << 1), 64);
        if (lr < 8)
          hid[(size_t)(row + rr) * FDIM + fbase + nf * 8 + (l & 7)] = f2b(vc);
      }
  }
}

// ---------------- GEMM2: 128x128 tile, 2-barrier; dense bf16 eo stores --------------
__global__ void moe_gemm2(const unsigned short* __restrict__ A,
                          const unsigned short* __restrict__ B,
                          const int* __restrict__ base,
                          unsigned short* __restrict__ eo) {
  constexpr int KDIM = FDIM;      // 4096
  constexpr int NDIM = DDIM;      // 2048

  int mt, ntl;
  xcd_map2d(blockIdx.x, MAXMT / 8, NDIM / 128, mt, ntl);

  const int m0 = mt * 128;
  if (m0 >= base[8]) return;
  int e = 0;
  #pragma unroll
  for (int qq = 1; qq < 8; ++qq) if (m0 >= base[qq]) e = qq;
  const int n0 = ntl * 128;
  const unsigned short* Bp = B + (size_t)e * NDIM * KDIM;

  __shared__ __align__(16) unsigned short As[128 * 64];
  __shared__ __align__(16) unsigned short Bs[128 * 64];

  const int tid = threadIdx.x;
  const int l = tid & 63;
  const int w = tid >> 6;
  const int wm = w >> 1, wn = w & 1;
  const int lr = l & 15, kc = l >> 4;

  const f32x4 vzero = {0.f, 0.f, 0.f, 0.f};
  f32x4 acc[4][4];
  #pragma unroll
  for (int i = 0; i < 4; ++i)
    #pragma unroll
    for (int j = 0; j < 4; ++j) acc[i][j] = vzero;

  const int srow = w * 32 + (l >> 3);
  const int sc = l & 7;
  const unsigned short* Arow = A + (size_t)(m0 + srow) * KDIM;
  const unsigned short* Brow = Bp + (size_t)(n0 + srow) * KDIM;

  for (int k0 = 0; k0 < KDIM; k0 += 64) {
    #pragma unroll
    for (int qq = 0; qq < 4; ++qq) {
      const int r = srow + qq * 8;
      const int cg = (sc ^ (r & 7)) << 3;
      gload_lds16(Arow + (size_t)qq * 8 * KDIM + k0 + cg,
                  (unsigned short*)As + w * 2048 + qq * 512);
      gload_lds16(Brow + (size_t)qq * 8 * KDIM + k0 + cg,
                  (unsigned short*)Bs + w * 2048 + qq * 512);
    }
    __syncthreads();
    #pragma unroll
    for (int ks = 0; ks < 2; ++ks) {
      bf16x8 af[4], bfr[4];
      #pragma unroll
      for (int mf = 0; mf < 4; ++mf) {
        const int r = wm * 64 + mf * 16 + lr;
        const int c = (ks * 4 + kc) ^ (r & 7);
        af[mf] = *(const bf16x8*)((const char*)As + r * 128 + c * 16);
      }
      #pragma unroll
      for (int nf = 0; nf < 4; ++nf) {
        const int n = wn * 64 + nf * 16 + lr;
        const int c = (ks * 4 + kc) ^ (n & 7);
        bfr[nf] = *(const bf16x8*)((const char*)Bs + n * 128 + c * 16);
      }
      #pragma unroll
      for (int mf = 0; mf < 4; ++mf)
        #pragma unroll
        for (int nf = 0; nf < 4; ++nf)
          acc[mf][nf] = __builtin_amdgcn_mfma_f32_16x16x32_bf16(af[mf], bfr[nf], acc[mf][nf], 0, 0, 0);
    }
    __syncthreads();
  }
  // epilogue: plain bf16 stores (token combine happens in a separate kernel)
  #pragma unroll
  for (int mf = 0; mf < 4; ++mf) {
    const int row = m0 + wm * 64 + mf * 16 + (kc << 2);
    #pragma unroll
    for (int rr = 0; rr < 4; ++rr) {
      unsigned short* erow = eo + (size_t)(row + rr) * DDIM;
      #pragma unroll
      for (int nf = 0; nf < 4; ++nf) {
        const int col = n0 + wn * 64 + nf * 16 + lr;
        erow[col] = f2b(acc[mf][nf][rr]);
      }
    }
  }
}

// ---------------- combine: out[t] = w0*eo[row0] + w1*eo[row1] ----------------
__global__ void combine_k(const unsigned short* __restrict__ eo,
                          const int* __restrict__ trow, const float* __restrict__ sel_w,
                          float* __restrict__ out) {
  const int t = blockIdx.x;
  const int r0 = trow[t * 2], r1 = trow[t * 2 + 1];
  const float w0 = sel_w[t * 2], w1 = sel_w[t * 2 + 1];
  const int c = threadIdx.x * 8;
  union { uint4 u; unsigned short s[8]; } a, b;
  a.u = *(const uint4*)(eo + (size_t)r0 * DDIM + c);
  b.u = *(const uint4*)(eo + (size_t)r1 * DDIM + c);
  float o[8];
  #pragma unroll
  for (int j = 0; j < 8; ++j) {
    union { unsigned u; float f; } fa, fb;
    fa.u = (unsigned)a.s[j] << 16;
    fb.u = (unsigned)b.s[j] << 16;
    o[j] = w0 * fa.f + w1 * fb.f;
  }
  float4* dst = (float4*)(out + (size_t)t * DDIM + c);
  dst[0] = make_float4(o[0], o[1], o[2], o[3]);
  dst[1] = make_float4(o[4], o[5], o[6], o[7]);
}

// ---------------- launch ----------------
// ws layout (bytes)
#define OFF_CNT   0u
#define OFF_BASE  64u
#define OFF_SELE  4096u
#define OFF_SELW  36864u
#define OFF_RTOK  69632u
#define OFF_RGW   106496u
#define OFF_TROW  143360u       // 4096*2 int = 32768 -> 176128
#define OFF_XC    1048576u      // 9216*2048 bf16 = 37748736 (eo aliases this after gemm1)
#define OFF_HID   38797312u     // 9216*4096 bf16 = 75497472
#define OFF_WBUF  114294784u    // 8*8192*2048 bf16 = 268435456 -> end ~365 MB

extern "C" void kernel_launch(void* const* d_in, const int* in_sizes, int n_in,
                              void* d_out, int out_size, void* d_ws, size_t ws_size,
                              hipStream_t stream) {
  const float* x  = (const float*)d_in[0];
  const float* gw = (const float*)d_in[1];
  const float* w1 = (const float*)d_in[2];
  const float* w3 = (const float*)d_in[3];
  const float* w2 = (const float*)d_in[4];
  float* out = (float*)d_out;
  char* ws = (char*)d_ws;

  int*   cnt   = (int*)(ws + OFF_CNT);
  int*   base  = (int*)(ws + OFF_BASE);
  int*   sel_e = (int*)(ws + OFF_SELE);
  float* sel_w = (float*)(ws + OFF_SELW);
  int*   rtok  = (int*)(ws + OFF_RTOK);
  float* rgw   = (float*)(ws + OFF_RGW);
  int*   trow  = (int*)(ws + OFF_TROW);
  unsigned short* xc   = (unsigned short*)(ws + OFF_XC);
  unsigned short* hid  = (unsigned short*)(ws + OFF_HID);
  unsigned short* wbuf = (unsigned short*)(ws + OFF_WBUF);
  unsigned short* eo   = xc;   // xc is dead after gemm1; reuse for expert outputs

  gate_topk<<<T_TOK / 4, 256, 0, stream>>>(x, gw, sel_e, sel_w);
  build_lists<<<1, 256, 0, stream>>>(sel_e, sel_w, cnt, base, rtok, rgw, trow);
  gather_x<<<MAXROWS, 256, 0, stream>>>(x, base, rtok, xc);
  // w13t[e][8192][2048]: even rows = w1 cols, odd rows = w3 cols (one dispatch)
  conv_w13<<<dim3(32, 64, 16), 256, 0, stream>>>(w1, w3, wbuf);
  // gemm1: 72*64 = 4608 blocks, 2D-chunked XCD map
  moe_gemm1<<<MAXMT * 64, 256, 0, stream>>>(xc, wbuf, base, hid);
  // reuse wbuf for w2t[e][2048][4096]
  conv_w2<<<dim3(64, 32, 8), 256, 0, stream>>>(w2, wbuf);
  // gemm2: 72*16 = 1152 blocks, 2D-chunked XCD map; dense eo stores
  moe_gemm2<<<MAXMT * 16, 256, 0, stream>>>(hid, wbuf, base, eo);
  combine_k<<<T_TOK, 256, 0, stream>>>(eo, trow, sel_w, out);
}

// Round 9
// 777.988 us; speedup vs baseline: 1.2473x; 1.0100x over previous
//
#include <hip/hip_runtime.h>
#include <hip/hip_bf16.h>

#define T_TOK 4096
#define DDIM  2048
#define FDIM  4096
#define NEXP  8
#define MAXROWS 9216   // T*2 + 8*128 padding
#define MAXMT   72     // MAXROWS/128
#define G1_GRID (MAXMT * 64)        // 4608 gemm1 blocks
#define CV2_GRID 16384              // conv_w2 tile blocks (8e * 64f * 32d)
// fused grid: 512 groups of 41 = [9 gemm | 32 conv]; 41%8==9%8==1 keeps XCD map valid
#define FUSED_GRID (512 * 41)

typedef __attribute__((ext_vector_type(4))) float f32x4;
typedef __attribute__((ext_vector_type(8))) short bf16x8;

__device__ __forceinline__ unsigned short f2b(float f) {
  union { float f; unsigned u; } c; c.f = f;
  unsigned r = c.u + 0x7FFFu + ((c.u >> 16) & 1u);
  return (unsigned short)(r >> 16);
}

// async global->LDS, 16B per lane; LDS dest must be wave-uniform base (+lane*16 implicit)
__device__ __forceinline__ void gload_lds16(const void* g, void* l) {
  __builtin_amdgcn_global_load_lds((__attribute__((address_space(1))) void*)(g),
                                   (__attribute__((address_space(3))) void*)(l),
                                   16, 0, 0);
}

// 2D-chunked XCD block mapping: XCD x owns m-tiles [x*MT_PER, +MT_PER), sweeps n
// in groups of 4. B-panel reuse distance = 4 blocks (L2-hot); A-chunk L2/L3-resident.
__device__ __forceinline__ void xcd_map2d(int bid, int MT_PER, int NT, int& mt, int& nt) {
  const int xcd = bid & 7;
  const int li = bid >> 3;
  const int grp = MT_PER * 4;
  const int ng = li / grp;
  const int rem = li % grp;
  mt = xcd * MT_PER + (rem >> 2);
  nt = ng * 4 + (rem & 3);
}

// ---------------- gating: one wave per token ----------------
__global__ void gate_topk(const float* __restrict__ x, const float* __restrict__ gw,
                          int* __restrict__ sel_e, float* __restrict__ sel_w) {
  const int t = blockIdx.x * 4 + (threadIdx.x >> 6);
  const int l = threadIdx.x & 63;
  const float* xr = x + (size_t)t * DDIM;
  float acc[8];
  #pragma unroll
  for (int e = 0; e < 8; ++e) acc[e] = 0.f;
  for (int d = l; d < DDIM; d += 64) {
    const float xv = xr[d];
    const float* g = gw + d * 8;
    #pragma unroll
    for (int e = 0; e < 8; ++e) acc[e] = fmaf(xv, g[e], acc[e]);
  }
  #pragma unroll
  for (int e = 0; e < 8; ++e) {
    float v = acc[e];
    #pragma unroll
    for (int off = 32; off; off >>= 1) v += __shfl_xor(v, off, 64);
    acc[e] = v;
  }
  if (l == 0) {
    int e0 = 0; float v0 = acc[0];
    #pragma unroll
    for (int e = 1; e < 8; ++e) if (acc[e] > v0) { v0 = acc[e]; e0 = e; }
    int e1 = -1; float v1 = -1e30f;
    #pragma unroll
    for (int e = 0; e < 8; ++e) if (e != e0 && acc[e] > v1) { v1 = acc[e]; e1 = e; }
    const float ex = __expf(v1 - v0);
    const float w0 = 1.f / (1.f + ex);
    sel_e[t * 2] = e0; sel_e[t * 2 + 1] = e1;
    sel_w[t * 2] = w0; sel_w[t * 2 + 1] = ex * w0;
  }
}

// ---------------- per-expert lists (single block) ----------------
__global__ void build_lists(const int* __restrict__ sel_e, const float* __restrict__ sel_w,
                            int* __restrict__ cnt, int* __restrict__ base,
                            int* __restrict__ row_token, float* __restrict__ row_gw,
                            int* __restrict__ trow) {
  __shared__ int c[8], f[8], b[9];
  const int tid = threadIdx.x;
  if (tid < 8) { c[tid] = 0; f[tid] = 0; }
  __syncthreads();
  for (int t = tid; t < T_TOK; t += 256) {
    atomicAdd(&c[sel_e[t * 2]], 1);
    atomicAdd(&c[sel_e[t * 2 + 1]], 1);
  }
  __syncthreads();
  if (tid == 0) {
    int r = 0;
    for (int e = 0; e < 8; ++e) { b[e] = r; r += ((c[e] + 127) >> 7) << 7; }
    b[8] = r;
    for (int e = 0; e < 8; ++e) { cnt[e] = c[e]; base[e] = b[e]; }
    base[8] = r;
  }
  __syncthreads();
  for (int i = tid; i < MAXROWS; i += 256) { row_token[i] = -1; row_gw[i] = 0.f; }
  __syncthreads();
  for (int t = tid; t < T_TOK; t += 256) {
    #pragma unroll
    for (int k = 0; k < 2; ++k) {
      const int e = sel_e[t * 2 + k];
      const int p = b[e] + atomicAdd(&f[e], 1);
      row_token[p] = t; row_gw[p] = sel_w[t * 2 + k];
      trow[t * 2 + k] = p;                       // inverse map for combine
    }
  }
}

// ---------------- gather x rows -> compact bf16 ----------------
__global__ void gather_x(const float* __restrict__ x, const int* __restrict__ base,
                         const int* __restrict__ row_token, unsigned short* __restrict__ xc) {
  const int i = blockIdx.x;
  if (i >= base[8]) return;
  const int t = row_token[i];
  const int tid = threadIdx.x;
  union { uint4 u; unsigned short s[8]; } o;
  if (t < 0) { o.u.x = 0u; o.u.y = 0u; o.u.z = 0u; o.u.w = 0u; }
  else {
    const float4* src = (const float4*)(x + (size_t)t * DDIM + tid * 8);
    const float4 a = src[0], bb = src[1];
    o.s[0] = f2b(a.x);  o.s[1] = f2b(a.y);  o.s[2] = f2b(a.z);  o.s[3] = f2b(a.w);
    o.s[4] = f2b(bb.x); o.s[5] = f2b(bb.y); o.s[6] = f2b(bb.z); o.s[7] = f2b(bb.w);
  }
  ((uint4*)(xc + (size_t)i * DDIM))[tid] = o.u;
}

// ---------------- transpose + fp32->bf16 convert (shared tile passed in) ------------
__device__ __forceinline__ void conv_tile(const float* s, unsigned short* d,
                                          int R, int C, int rowMul, int rowAdd,
                                          int r0, int c0, int tid,
                                          unsigned short (*T)[68]) {
  {
    const int i = tid >> 2, jb = (tid & 3) * 16;
    #pragma unroll
    for (int k2 = 0; k2 < 4; ++k2) {
      const float4 v = *(const float4*)(s + (size_t)(r0 + i) * C + c0 + jb + k2 * 4);
      uint2 uu;
      uu.x = (unsigned)f2b(v.x) | ((unsigned)f2b(v.y) << 16);
      uu.y = (unsigned)f2b(v.z) | ((unsigned)f2b(v.w) << 16);
      *(uint2*)&T[i][jb + k2 * 4] = uu;
    }
  }
  __syncthreads();
  {
    const int j = tid >> 2, ib = (tid & 3) * 16;
    union { uint4 q[2]; unsigned short s16[16]; } pk;
    #pragma unroll
    for (int i = 0; i < 16; ++i) pk.s16[i] = T[ib + i][j];
    unsigned short* drow = d + (size_t)(rowMul * (c0 + j) + rowAdd) * R + r0 + ib;
    *(uint4*)drow = pk.q[0];
    *(uint4*)(drow + 8) = pk.q[1];
  }
}

// merged w1+w3 conversion: z<8 -> w1 (rowAdd 0), z>=8 -> w3 (rowAdd 1)
__global__ void conv_w13(const float* __restrict__ w1, const float* __restrict__ w3,
                         unsigned short* __restrict__ dst) {
  __shared__ unsigned short T[64][68];
  const int z = blockIdx.z;
  const int e = z & 7;
  const int isw3 = z >> 3;
  const float* s = (isw3 ? w3 : w1) + (size_t)e * DDIM * FDIM;
  unsigned short* d = dst + (size_t)e * DDIM * FDIM * 2;
  conv_tile(s, d, DDIM, FDIM, 2, isw3, blockIdx.x * 64, blockIdx.y * 64, threadIdx.x, T);
}

// standalone conv_w2 (fallback path when ws too small for overlap buffer)
__global__ void conv_w2(const float* __restrict__ w2, unsigned short* __restrict__ dst) {
  __shared__ unsigned short T[64][68];
  const int e = blockIdx.z;
  const float* s = w2 + (size_t)e * FDIM * DDIM;
  unsigned short* d = dst + (size_t)e * FDIM * DDIM;
  conv_tile(s, d, FDIM, DDIM, 1, 0, blockIdx.x * 64, blockIdx.y * 64, threadIdx.x, T);
}

// ---------------- GEMM1 body: 128x128 tile, BK=64, 4 waves, 2-barrier (proven) ------
__device__ __forceinline__ void gemm1_body(int bid,
                                           const unsigned short* __restrict__ A,
                                           const unsigned short* __restrict__ B,
                                           const int* __restrict__ base,
                                           unsigned short* __restrict__ hid,
                                           unsigned short* As, unsigned short* Bs) {
  constexpr int KDIM = DDIM;      // 2048
  constexpr int NDIM = 2 * FDIM;  // 8192

  int mt, nt;
  xcd_map2d(bid, MAXMT / 8, NDIM / 128, mt, nt);

  const int m0 = mt * 128;
  if (m0 >= base[8]) return;
  int e = 0;
  #pragma unroll
  for (int qq = 1; qq < 8; ++qq) if (m0 >= base[qq]) e = qq;
  const int n0 = nt * 128;
  const unsigned short* Bp = B + (size_t)e * NDIM * KDIM;

  const int tid = threadIdx.x;
  const int l = tid & 63;
  const int w = tid >> 6;
  const int wm = w >> 1, wn = w & 1;
  const int lr = l & 15, kc = l >> 4;

  const f32x4 vzero = {0.f, 0.f, 0.f, 0.f};
  f32x4 acc[4][4];
  #pragma unroll
  for (int i = 0; i < 4; ++i)
    #pragma unroll
    for (int j = 0; j < 4; ++j) acc[i][j] = vzero;

  const int srow = w * 32 + (l >> 3);
  const int sc = l & 7;
  const unsigned short* Arow = A + (size_t)(m0 + srow) * KDIM;
  const unsigned short* Brow = Bp + (size_t)(n0 + srow) * KDIM;

  for (int k0 = 0; k0 < KDIM; k0 += 64) {
    #pragma unroll
    for (int qq = 0; qq < 4; ++qq) {
      const int r = srow + qq * 8;
      const int cg = (sc ^ (r & 7)) << 3;
      gload_lds16(Arow + (size_t)qq * 8 * KDIM + k0 + cg, As + w * 2048 + qq * 512);
      gload_lds16(Brow + (size_t)qq * 8 * KDIM + k0 + cg, Bs + w * 2048 + qq * 512);
    }
    __syncthreads();
    #pragma unroll
    for (int ks = 0; ks < 2; ++ks) {
      bf16x8 af[4], bfr[4];
      #pragma unroll
      for (int mf = 0; mf < 4; ++mf) {
        const int r = wm * 64 + mf * 16 + lr;
        const int c = (ks * 4 + kc) ^ (r & 7);
        af[mf] = *(const bf16x8*)((const char*)As + r * 128 + c * 16);
      }
      #pragma unroll
      for (int nf = 0; nf < 4; ++nf) {
        const int n = wn * 64 + nf * 16 + lr;
        const int c = (ks * 4 + kc) ^ (n & 7);
        bfr[nf] = *(const bf16x8*)((const char*)Bs + n * 128 + c * 16);
      }
      #pragma unroll
      for (int mf = 0; mf < 4; ++mf)
        #pragma unroll
        for (int nf = 0; nf < 4; ++nf)
          acc[mf][nf] = __builtin_amdgcn_mfma_f32_16x16x32_bf16(af[mf], bfr[nf], acc[mf][nf], 0, 0, 0);
    }
    __syncthreads();
  }

  // epilogue: cols interleaved even=h(w1), odd=g(w3); out col = global_col/2
  const int fbase = (n0 >> 1) + wn * 32;
  #pragma unroll
  for (int mf = 0; mf < 4; ++mf) {
    const int row = m0 + wm * 64 + mf * 16 + (kc << 2);
    #pragma unroll
    for (int nf = 0; nf < 4; ++nf)
      #pragma unroll
      for (int rr = 0; rr < 4; ++rr) {
        const float v = acc[mf][nf][rr];
        const float o = __shfl_xor(v, 1, 64);
        const float h = (l & 1) ? o : v;
        const float g = (l & 1) ? v : o;
        const float res = (h / (1.f + __expf(-h))) * g;
        const float vc = __shfl(res, (l & 48) | ((l & 7) << 1), 64);
        if (lr < 8)
          hid[(size_t)(row + rr) * FDIM + fbase + nf * 8 + (l & 7)] = f2b(vc);
      }
  }
}

// standalone gemm1 (fallback path)
__global__ void moe_gemm1(const unsigned short* __restrict__ A,
                          const unsigned short* __restrict__ B,
                          const int* __restrict__ base,
                          unsigned short* __restrict__ hid) {
  __shared__ __align__(16) unsigned short As[128 * 64];
  __shared__ __align__(16) unsigned short Bs[128 * 64];
  gemm1_body(blockIdx.x, A, B, base, hid, As, Bs);
}

// ---------------- fused: gemm1 blocks co-dispatched with conv_w2 tile blocks --------
// Per 41-block group: ids 0-8 -> gemm1 (compute-bound, ~26% HBM), ids 9-40 -> conv_w2
// (pure memory). Interleave fills gemm1's idle HBM with the w2 conversion traffic.
// conv writes w2t (separate ws region; no alias with w13t that gemm reads).
__global__ void gemm1_fused(const unsigned short* __restrict__ A,
                            const unsigned short* __restrict__ B,
                            const int* __restrict__ base,
                            unsigned short* __restrict__ hid,
                            const float* __restrict__ w2,
                            unsigned short* __restrict__ w2t) {
  __shared__ __align__(16) unsigned short As[128 * 64];
  __shared__ __align__(16) unsigned short Bs[128 * 64];
  const int g = blockIdx.x / 41;
  const int r = blockIdx.x % 41;
  if (r < 9) {
    gemm1_body(g * 9 + r, A, B, base, hid, As, Bs);
  } else {
    const int cid = g * 32 + (r - 9);          // 0..16383
    const int e = cid >> 11;                   // 2048 tiles per expert
    const int rem = cid & 2047;
    const int r0 = (rem >> 5) * 64;            // over F (4096)
    const int c0 = (rem & 31) * 64;            // over D (2048)
    conv_tile(w2 + (size_t)e * FDIM * DDIM, w2t + (size_t)e * FDIM * DDIM,
              FDIM, DDIM, 1, 0, r0, c0, threadIdx.x, (unsigned short (*)[68])As);
  }
}

// ---------------- GEMM2: 128x128 tile, 2-barrier; dense bf16 eo stores --------------
__global__ void moe_gemm2(const unsigned short* __restrict__ A,
                          const unsigned short* __restrict__ B,
                          const int* __restrict__ base,
                          unsigned short* __restrict__ eo) {
  constexpr int KDIM = FDIM;      // 4096
  constexpr int NDIM = DDIM;      // 2048

  int mt, ntl;
  xcd_map2d(blockIdx.x, MAXMT / 8, NDIM / 128, mt, ntl);

  const int m0 = mt * 128;
  if (m0 >= base[8]) return;
  int e = 0;
  #pragma unroll
  for (int qq = 1; qq < 8; ++qq) if (m0 >= base[qq]) e = qq;
  const int n0 = ntl * 128;
  const unsigned short* Bp = B + (size_t)e * NDIM * KDIM;

  __shared__ __align__(16) unsigned short As[128 * 64];
  __shared__ __align__(16) unsigned short Bs[128 * 64];

  const int tid = threadIdx.x;
  const int l = tid & 63;
  const int w = tid >> 6;
  const int wm = w >> 1, wn = w & 1;
  const int lr = l & 15, kc = l >> 4;

  const f32x4 vzero = {0.f, 0.f, 0.f, 0.f};
  f32x4 acc[4][4];
  #pragma unroll
  for (int i = 0; i < 4; ++i)
    #pragma unroll
    for (int j = 0; j < 4; ++j) acc[i][j] = vzero;

  const int srow = w * 32 + (l >> 3);
  const int sc = l & 7;
  const unsigned short* Arow = A + (size_t)(m0 + srow) * KDIM;
  const unsigned short* Brow = Bp + (size_t)(n0 + srow) * KDIM;

  for (int k0 = 0; k0 < KDIM; k0 += 64) {
    #pragma unroll
    for (int qq = 0; qq < 4; ++qq) {
      const int r = srow + qq * 8;
      const int cg = (sc ^ (r & 7)) << 3;
      gload_lds16(Arow + (size_t)qq * 8 * KDIM + k0 + cg,
                  (unsigned short*)As + w * 2048 + qq * 512);
      gload_lds16(Brow + (size_t)qq * 8 * KDIM + k0 + cg,
                  (unsigned short*)Bs + w * 2048 + qq * 512);
    }
    __syncthreads();
    #pragma unroll
    for (int ks = 0; ks < 2; ++ks) {
      bf16x8 af[4], bfr[4];
      #pragma unroll
      for (int mf = 0; mf < 4; ++mf) {
        const int r = wm * 64 + mf * 16 + lr;
        const int c = (ks * 4 + kc) ^ (r & 7);
        af[mf] = *(const bf16x8*)((const char*)As + r * 128 + c * 16);
      }
      #pragma unroll
      for (int nf = 0; nf < 4; ++nf) {
        const int n = wn * 64 + nf * 16 + lr;
        const int c = (ks * 4 + kc) ^ (n & 7);
        bfr[nf] = *(const bf16x8*)((const char*)Bs + n * 128 + c * 16);
      }
      #pragma unroll
      for (int mf = 0; mf < 4; ++mf)
        #pragma unroll
        for (int nf = 0; nf < 4; ++nf)
          acc[mf][nf] = __builtin_amdgcn_mfma_f32_16x16x32_bf16(af[mf], bfr[nf], acc[mf][nf], 0, 0, 0);
    }
    __syncthreads();
  }
  #pragma unroll
  for (int mf = 0; mf < 4; ++mf) {
    const int row = m0 + wm * 64 + mf * 16 + (kc << 2);
    #pragma unroll
    for (int rr = 0; rr < 4; ++rr) {
      unsigned short* erow = eo + (size_t)(row + rr) * DDIM;
      #pragma unroll
      for (int nf = 0; nf < 4; ++nf) {
        const int col = n0 + wn * 64 + nf * 16 + lr;
        erow[col] = f2b(acc[mf][nf][rr]);
      }
    }
  }
}

// ---------------- combine: out[t] = w0*eo[row0] + w1*eo[row1] ----------------
__global__ void combine_k(const unsigned short* __restrict__ eo,
                          const int* __restrict__ trow, const float* __restrict__ sel_w,
                          float* __restrict__ out) {
  const int t = blockIdx.x;
  const int r0 = trow[t * 2], r1 = trow[t * 2 + 1];
  const float w0 = sel_w[t * 2], w1 = sel_w[t * 2 + 1];
  const int c = threadIdx.x * 8;
  union { uint4 u; unsigned short s[8]; } a, b;
  a.u = *(const uint4*)(eo + (size_t)r0 * DDIM + c);
  b.u = *(const uint4*)(eo + (size_t)r1 * DDIM + c);
  float o[8];
  #pragma unroll
  for (int j = 0; j < 8; ++j) {
    union { unsigned u; float f; } fa, fb;
    fa.u = (unsigned)a.s[j] << 16;
    fb.u = (unsigned)b.s[j] << 16;
    o[j] = w0 * fa.f + w1 * fb.f;
  }
  float4* dst = (float4*)(out + (size_t)t * DDIM + c);
  dst[0] = make_float4(o[0], o[1], o[2], o[3]);
  dst[1] = make_float4(o[4], o[5], o[6], o[7]);
}

// ---------------- launch ----------------
// ws layout (bytes)
#define OFF_CNT   0u
#define OFF_BASE  64u
#define OFF_SELE  4096u
#define OFF_SELW  36864u
#define OFF_RTOK  69632u
#define OFF_RGW   106496u
#define OFF_TROW  143360u
#define OFF_XC    1048576u              // 9216*2048 bf16 (eo aliases after gemm1)
#define OFF_HID   38797312u             // 9216*4096 bf16
#define OFF_WBUF  114294784u            // w13t: 8*8192*2048 bf16 = 268435456
#define OFF_W2T   382730240ull          // w2t:  8*2048*4096 bf16 = 134217728
#define WS_NEED   516947968ull          // OFF_W2T + w2t size

extern "C" void kernel_launch(void* const* d_in, const int* in_sizes, int n_in,
                              void* d_out, int out_size, void* d_ws, size_t ws_size,
                              hipStream_t stream) {
  const float* x  = (const float*)d_in[0];
  const float* gw = (const float*)d_in[1];
  const float* w1 = (const float*)d_in[2];
  const float* w3 = (const float*)d_in[3];
  const float* w2 = (const float*)d_in[4];
  float* out = (float*)d_out;
  char* ws = (char*)d_ws;

  int*   cnt   = (int*)(ws + OFF_CNT);
  int*   base  = (int*)(ws + OFF_BASE);
  int*   sel_e = (int*)(ws + OFF_SELE);
  float* sel_w = (float*)(ws + OFF_SELW);
  int*   rtok  = (int*)(ws + OFF_RTOK);
  float* rgw   = (float*)(ws + OFF_RGW);
  int*   trow  = (int*)(ws + OFF_TROW);
  unsigned short* xc   = (unsigned short*)(ws + OFF_XC);
  unsigned short* hid  = (unsigned short*)(ws + OFF_HID);
  unsigned short* wbuf = (unsigned short*)(ws + OFF_WBUF);
  unsigned short* w2t  = (unsigned short*)(ws + OFF_W2T);
  unsigned short* eo   = xc;   // xc is dead after gemm1; reuse for expert outputs

  const bool fused = (ws_size >= WS_NEED);

  gate_topk<<<T_TOK / 4, 256, 0, stream>>>(x, gw, sel_e, sel_w);
  build_lists<<<1, 256, 0, stream>>>(sel_e, sel_w, cnt, base, rtok, rgw, trow);
  gather_x<<<MAXROWS, 256, 0, stream>>>(x, base, rtok, xc);
  // w13t[e][8192][2048]: even rows = w1 cols, odd rows = w3 cols
  conv_w13<<<dim3(32, 64, 16), 256, 0, stream>>>(w1, w3, wbuf);

  if (fused) {
    // gemm1 (4608 blocks) co-dispatched with conv_w2 (16384 blocks), 9:32 interleave
    gemm1_fused<<<FUSED_GRID, 256, 0, stream>>>(xc, wbuf, base, hid, w2, w2t);
    moe_gemm2<<<MAXMT * 16, 256, 0, stream>>>(hid, w2t, base, eo);
  } else {
    moe_gemm1<<<G1_GRID, 256, 0, stream>>>(xc, wbuf, base, hid);
    conv_w2<<<dim3(64, 32, 8), 256, 0, stream>>>(w2, wbuf);  // alias w13t (dead)
    moe_gemm2<<<MAXMT * 16, 256, 0, stream>>>(hid, wbuf, base, eo);
  }
  combine_k<<<T_TOK, 256, 0, stream>>>(eo, trow, sel_w, out);
}

// Round 10
// 770.970 us; speedup vs baseline: 1.2587x; 1.0091x over previous
//
#include <hip/hip_runtime.h>
#include <hip/hip_bf16.h>

#define T_TOK 4096
#define DDIM  2048
#define FDIM  4096
#define NEXP  8
#define MAXROWS 9216   // T*2 + 8*128 padding
#define MAXMT   72     // MAXROWS/128
#define G1_GRID (MAXMT * 64)        // 4608 gemm1 blocks
#define CONV13_BLOCKS 32768         // 16z * 32x * 64y tiles of 64x64
// fused grid: 512 groups of 17 = [9 gemm | 8 conv]; 17%8==9%8==1 keeps XCD map valid
#define FUSED_GRID (512 * 17)

typedef __attribute__((ext_vector_type(4))) float f32x4;
typedef __attribute__((ext_vector_type(8))) short bf16x8;

__device__ __forceinline__ unsigned short f2b(float f) {
  union { float f; unsigned u; } c; c.f = f;
  unsigned r = c.u + 0x7FFFu + ((c.u >> 16) & 1u);
  return (unsigned short)(r >> 16);
}

// async global->LDS, 16B per lane; LDS dest must be wave-uniform base (+lane*16 implicit)
__device__ __forceinline__ void gload_lds16(const void* g, void* l) {
  __builtin_amdgcn_global_load_lds((__attribute__((address_space(1))) void*)(g),
                                   (__attribute__((address_space(3))) void*)(l),
                                   16, 0, 0);
}

// 2D-chunked XCD block mapping: XCD x owns m-tiles [x*MT_PER, +MT_PER), sweeps n
// in groups of 4. B-panel reuse distance = 4 blocks (L2-hot); A-chunk L2/L3-resident.
__device__ __forceinline__ void xcd_map2d(int bid, int MT_PER, int NT, int& mt, int& nt) {
  const int xcd = bid & 7;
  const int li = bid >> 3;
  const int grp = MT_PER * 4;
  const int ng = li / grp;
  const int rem = li % grp;
  mt = xcd * MT_PER + (rem >> 2);
  nt = ng * 4 + (rem & 3);
}

// ---------------- gating: one wave per token ----------------
__global__ void gate_topk(const float* __restrict__ x, const float* __restrict__ gw,
                          int* __restrict__ sel_e, float* __restrict__ sel_w) {
  const int t = blockIdx.x * 4 + (threadIdx.x >> 6);
  const int l = threadIdx.x & 63;
  const float* xr = x + (size_t)t * DDIM;
  float acc[8];
  #pragma unroll
  for (int e = 0; e < 8; ++e) acc[e] = 0.f;
  for (int d = l; d < DDIM; d += 64) {
    const float xv = xr[d];
    const float* g = gw + d * 8;
    #pragma unroll
    for (int e = 0; e < 8; ++e) acc[e] = fmaf(xv, g[e], acc[e]);
  }
  #pragma unroll
  for (int e = 0; e < 8; ++e) {
    float v = acc[e];
    #pragma unroll
    for (int off = 32; off; off >>= 1) v += __shfl_xor(v, off, 64);
    acc[e] = v;
  }
  if (l == 0) {
    int e0 = 0; float v0 = acc[0];
    #pragma unroll
    for (int e = 1; e < 8; ++e) if (acc[e] > v0) { v0 = acc[e]; e0 = e; }
    int e1 = -1; float v1 = -1e30f;
    #pragma unroll
    for (int e = 0; e < 8; ++e) if (e != e0 && acc[e] > v1) { v1 = acc[e]; e1 = e; }
    const float ex = __expf(v1 - v0);
    const float w0 = 1.f / (1.f + ex);
    sel_e[t * 2] = e0; sel_e[t * 2 + 1] = e1;
    sel_w[t * 2] = w0; sel_w[t * 2 + 1] = ex * w0;
  }
}

// ---------------- per-expert lists (single block) ----------------
__global__ void build_lists(const int* __restrict__ sel_e, const float* __restrict__ sel_w,
                            int* __restrict__ cnt, int* __restrict__ base,
                            int* __restrict__ row_token, float* __restrict__ row_gw,
                            int* __restrict__ trow) {
  __shared__ int c[8], f[8], b[9];
  const int tid = threadIdx.x;
  if (tid < 8) { c[tid] = 0; f[tid] = 0; }
  __syncthreads();
  for (int t = tid; t < T_TOK; t += 256) {
    atomicAdd(&c[sel_e[t * 2]], 1);
    atomicAdd(&c[sel_e[t * 2 + 1]], 1);
  }
  __syncthreads();
  if (tid == 0) {
    int r = 0;
    for (int e = 0; e < 8; ++e) { b[e] = r; r += ((c[e] + 127) >> 7) << 7; }
    b[8] = r;
    for (int e = 0; e < 8; ++e) { cnt[e] = c[e]; base[e] = b[e]; }
    base[8] = r;
  }
  __syncthreads();
  for (int i = tid; i < MAXROWS; i += 256) { row_token[i] = -1; row_gw[i] = 0.f; }
  __syncthreads();
  for (int t = tid; t < T_TOK; t += 256) {
    #pragma unroll
    for (int k = 0; k < 2; ++k) {
      const int e = sel_e[t * 2 + k];
      const int p = b[e] + atomicAdd(&f[e], 1);
      row_token[p] = t; row_gw[p] = sel_w[t * 2 + k];
      trow[t * 2 + k] = p;                       // inverse map for combine
    }
  }
}

// ---------------- transpose + fp32->bf16 convert (shared tile passed in) ------------
// T padded to [64][70]: read stride 16*70*2B -> bank step 16 (2-way, free);
// stores split into 4B uints (row stride 140B breaks 8B alignment on odd rows).
__device__ __forceinline__ void conv_tile(const float* s, unsigned short* d,
                                          int R, int C, int rowMul, int rowAdd,
                                          int r0, int c0, int tid,
                                          unsigned short (*T)[70]) {
  {
    const int i = tid >> 2, jb = (tid & 3) * 16;
    #pragma unroll
    for (int k2 = 0; k2 < 4; ++k2) {
      const float4 v = *(const float4*)(s + (size_t)(r0 + i) * C + c0 + jb + k2 * 4);
      unsigned* p = (unsigned*)&T[i][jb + k2 * 4];
      p[0] = (unsigned)f2b(v.x) | ((unsigned)f2b(v.y) << 16);
      p[1] = (unsigned)f2b(v.z) | ((unsigned)f2b(v.w) << 16);
    }
  }
  __syncthreads();
  {
    const int j = tid >> 2, ib = (tid & 3) * 16;
    union { uint4 q[2]; unsigned short s16[16]; } pk;
    #pragma unroll
    for (int i = 0; i < 16; ++i) pk.s16[i] = T[ib + i][j];
    unsigned short* drow = d + (size_t)(rowMul * (c0 + j) + rowAdd) * R + r0 + ib;
    *(uint4*)drow = pk.q[0];
    *(uint4*)(drow + 8) = pk.q[1];
  }
}

// ---------------- conv_w13 tiles + gather_x rows in one dispatch --------------------
// blocks [0, CONV13_BLOCKS): w1/w3 -> w13t[e][8192][2048] (even rows w1, odd w3)
// blocks [CONV13_BLOCKS, +MAXROWS): gather x rows -> compact bf16 xc
__global__ void conv13_gather(const float* __restrict__ w1, const float* __restrict__ w3,
                              unsigned short* __restrict__ dst,
                              const float* __restrict__ x, const int* __restrict__ base,
                              const int* __restrict__ row_token,
                              unsigned short* __restrict__ xc) {
  __shared__ unsigned short T[64][70];
  const int bid = blockIdx.x;
  if (bid < CONV13_BLOCKS) {
    const int z = bid >> 11;               // 0..15
    const int y = (bid >> 5) & 63;         // over F/64
    const int xg = bid & 31;               // over D/64
    const int e = z & 7;
    const int isw3 = z >> 3;
    const float* s = (isw3 ? w3 : w1) + (size_t)e * DDIM * FDIM;
    unsigned short* d = dst + (size_t)e * DDIM * FDIM * 2;
    conv_tile(s, d, DDIM, FDIM, 2, isw3, xg * 64, y * 64, threadIdx.x, T);
  } else {
    const int i = bid - CONV13_BLOCKS;
    if (i >= base[8]) return;
    const int t = row_token[i];
    const int tid = threadIdx.x;
    union { uint4 u; unsigned short s[8]; } o;
    if (t < 0) { o.u.x = 0u; o.u.y = 0u; o.u.z = 0u; o.u.w = 0u; }
    else {
      const float4* src = (const float4*)(x + (size_t)t * DDIM + tid * 8);
      const float4 a = src[0], bb = src[1];
      o.s[0] = f2b(a.x);  o.s[1] = f2b(a.y);  o.s[2] = f2b(a.z);  o.s[3] = f2b(a.w);
      o.s[4] = f2b(bb.x); o.s[5] = f2b(bb.y); o.s[6] = f2b(bb.z); o.s[7] = f2b(bb.w);
    }
    ((uint4*)(xc + (size_t)i * DDIM))[tid] = o.u;
  }
}

// standalone conv_w2 (fallback path when ws too small for overlap buffer)
__global__ void conv_w2(const float* __restrict__ w2, unsigned short* __restrict__ dst) {
  __shared__ unsigned short T[64][70];
  const int e = blockIdx.z;
  const float* s = w2 + (size_t)e * FDIM * DDIM;
  unsigned short* d = dst + (size_t)e * FDIM * DDIM;
  conv_tile(s, d, FDIM, DDIM, 1, 0, blockIdx.x * 64, blockIdx.y * 64, threadIdx.x, T);
}

// ---------------- GEMM1 body: 128x128 tile, BK=64, 4 waves, 2-barrier (proven) ------
__device__ __forceinline__ void gemm1_body(int bid,
                                           const unsigned short* __restrict__ A,
                                           const unsigned short* __restrict__ B,
                                           const int* __restrict__ base,
                                           unsigned short* __restrict__ hid,
                                           unsigned short* As, unsigned short* Bs) {
  constexpr int KDIM = DDIM;      // 2048
  constexpr int NDIM = 2 * FDIM;  // 8192

  int mt, nt;
  xcd_map2d(bid, MAXMT / 8, NDIM / 128, mt, nt);

  const int m0 = mt * 128;
  if (m0 >= base[8]) return;
  int e = 0;
  #pragma unroll
  for (int qq = 1; qq < 8; ++qq) if (m0 >= base[qq]) e = qq;
  const int n0 = nt * 128;
  const unsigned short* Bp = B + (size_t)e * NDIM * KDIM;

  const int tid = threadIdx.x;
  const int l = tid & 63;
  const int w = tid >> 6;
  const int wm = w >> 1, wn = w & 1;
  const int lr = l & 15, kc = l >> 4;

  const f32x4 vzero = {0.f, 0.f, 0.f, 0.f};
  f32x4 acc[4][4];
  #pragma unroll
  for (int i = 0; i < 4; ++i)
    #pragma unroll
    for (int j = 0; j < 4; ++j) acc[i][j] = vzero;

  const int srow = w * 32 + (l >> 3);
  const int sc = l & 7;
  const unsigned short* Arow = A + (size_t)(m0 + srow) * KDIM;
  const unsigned short* Brow = Bp + (size_t)(n0 + srow) * KDIM;

  for (int k0 = 0; k0 < KDIM; k0 += 64) {
    #pragma unroll
    for (int qq = 0; qq < 4; ++qq) {
      const int r = srow + qq * 8;
      const int cg = (sc ^ (r & 7)) << 3;
      gload_lds16(Arow + (size_t)qq * 8 * KDIM + k0 + cg, As + w * 2048 + qq * 512);
      gload_lds16(Brow + (size_t)qq * 8 * KDIM + k0 + cg, Bs + w * 2048 + qq * 512);
    }
    __syncthreads();
    #pragma unroll
    for (int ks = 0; ks < 2; ++ks) {
      bf16x8 af[4], bfr[4];
      #pragma unroll
      for (int mf = 0; mf < 4; ++mf) {
        const int r = wm * 64 + mf * 16 + lr;
        const int c = (ks * 4 + kc) ^ (r & 7);
        af[mf] = *(const bf16x8*)((const char*)As + r * 128 + c * 16);
      }
      #pragma unroll
      for (int nf = 0; nf < 4; ++nf) {
        const int n = wn * 64 + nf * 16 + lr;
        const int c = (ks * 4 + kc) ^ (n & 7);
        bfr[nf] = *(const bf16x8*)((const char*)Bs + n * 128 + c * 16);
      }
      #pragma unroll
      for (int mf = 0; mf < 4; ++mf)
        #pragma unroll
        for (int nf = 0; nf < 4; ++nf)
          acc[mf][nf] = __builtin_amdgcn_mfma_f32_16x16x32_bf16(af[mf], bfr[nf], acc[mf][nf], 0, 0, 0);
    }
    __syncthreads();
  }

  // epilogue: cols interleaved even=h(w1), odd=g(w3); out col = global_col/2
  const int fbase = (n0 >> 1) + wn * 32;
  #pragma unroll
  for (int mf = 0; mf < 4; ++mf) {
    const int row = m0 + wm * 64 + mf * 16 + (kc << 2);
    #pragma unroll
    for (int nf = 0; nf < 4; ++nf)
      #pragma unroll
      for (int rr = 0; rr < 4; ++rr) {
        const float v = acc[mf][nf][rr];
        const float o = __shfl_xor(v, 1, 64);
        const float h = (l & 1) ? o : v;
        const float g = (l & 1) ? v : o;
        const float res = (h / (1.f + __expf(-h))) * g;
        const float vc = __shfl(res, (l & 48) | ((l & 7) << 1), 64);
        if (lr < 8)
          hid[(size_t)(row + rr) * FDIM + fbase + nf * 8 + (l & 7)] = f2b(vc);
      }
  }
}

// standalone gemm1 (fallback path)
__global__ void moe_gemm1(const unsigned short* __restrict__ A,
                          const unsigned short* __restrict__ B,
                          const int* __restrict__ base,
                          unsigned short* __restrict__ hid) {
  __shared__ __align__(16) unsigned short As[128 * 64];
  __shared__ __align__(16) unsigned short Bs[128 * 64];
  gemm1_body(blockIdx.x, A, B, base, hid, As, Bs);
}

// ---------------- fused: gemm1 blocks co-dispatched with conv_w2 work ---------------
// Per 17-block group: ids 0-8 -> gemm1, ids 9-16 -> conv_w2 unit (4 tiles each,
// 4096 units x 4 = 16384 tiles). Fewer, longer conv blocks cut per-block overhead.
// conv writes w2t (separate ws region; no alias with w13t that gemm reads).
__global__ void gemm1_fused(const unsigned short* __restrict__ A,
                            const unsigned short* __restrict__ B,
                            const int* __restrict__ base,
                            unsigned short* __restrict__ hid,
                            const float* __restrict__ w2,
                            unsigned short* __restrict__ w2t) {
  __shared__ __align__(16) unsigned short As[128 * 64];
  __shared__ __align__(16) unsigned short Bs[128 * 64];
  const int g = blockIdx.x / 17;
  const int r = blockIdx.x % 17;
  if (r < 9) {
    gemm1_body(g * 9 + r, A, B, base, hid, As, Bs);
  } else {
    const int u = g * 8 + (r - 9);             // 0..4095
    unsigned short (*T)[70] = (unsigned short (*)[70])As;  // 8960B, fits in As
    #pragma unroll
    for (int j = 0; j < 4; ++j) {
      const int cid = u * 4 + j;               // 0..16383
      const int e = cid >> 11;                 // 2048 tiles per expert
      const int rem = cid & 2047;
      const int r0 = (rem >> 5) * 64;          // over F (4096)
      const int c0 = (rem & 31) * 64;          // over D (2048)
      conv_tile(w2 + (size_t)e * FDIM * DDIM, w2t + (size_t)e * FDIM * DDIM,
                FDIM, DDIM, 1, 0, r0, c0, threadIdx.x, T);
      __syncthreads();                         // T reused next iteration
    }
  }
}

// ---------------- GEMM2: 128x128 tile, 2-barrier; dense bf16 eo stores --------------
__global__ void moe_gemm2(const unsigned short* __restrict__ A,
                          const unsigned short* __restrict__ B,
                          const int* __restrict__ base,
                          unsigned short* __restrict__ eo) {
  constexpr int KDIM = FDIM;      // 4096
  constexpr int NDIM = DDIM;      // 2048

  int mt, ntl;
  xcd_map2d(blockIdx.x, MAXMT / 8, NDIM / 128, mt, ntl);

  const int m0 = mt * 128;
  if (m0 >= base[8]) return;
  int e = 0;
  #pragma unroll
  for (int qq = 1; qq < 8; ++qq) if (m0 >= base[qq]) e = qq;
  const int n0 = ntl * 128;
  const unsigned short* Bp = B + (size_t)e * NDIM * KDIM;

  __shared__ __align__(16) unsigned short As[128 * 64];
  __shared__ __align__(16) unsigned short Bs[128 * 64];

  const int tid = threadIdx.x;
  const int l = tid & 63;
  const int w = tid >> 6;
  const int wm = w >> 1, wn = w & 1;
  const int lr = l & 15, kc = l >> 4;

  const f32x4 vzero = {0.f, 0.f, 0.f, 0.f};
  f32x4 acc[4][4];
  #pragma unroll
  for (int i = 0; i < 4; ++i)
    #pragma unroll
    for (int j = 0; j < 4; ++j) acc[i][j] = vzero;

  const int srow = w * 32 + (l >> 3);
  const int sc = l & 7;
  const unsigned short* Arow = A + (size_t)(m0 + srow) * KDIM;
  const unsigned short* Brow = Bp + (size_t)(n0 + srow) * KDIM;

  for (int k0 = 0; k0 < KDIM; k0 += 64) {
    #pragma unroll
    for (int qq = 0; qq < 4; ++qq) {
      const int r = srow + qq * 8;
      const int cg = (sc ^ (r & 7)) << 3;
      gload_lds16(Arow + (size_t)qq * 8 * KDIM + k0 + cg,
                  (unsigned short*)As + w * 2048 + qq * 512);
      gload_lds16(Brow + (size_t)qq * 8 * KDIM + k0 + cg,
                  (unsigned short*)Bs + w * 2048 + qq * 512);
    }
    __syncthreads();
    #pragma unroll
    for (int ks = 0; ks < 2; ++ks) {
      bf16x8 af[4], bfr[4];
      #pragma unroll
      for (int mf = 0; mf < 4; ++mf) {
        const int r = wm * 64 + mf * 16 + lr;
        const int c = (ks * 4 + kc) ^ (r & 7);
        af[mf] = *(const bf16x8*)((const char*)As + r * 128 + c * 16);
      }
      #pragma unroll
      for (int nf = 0; nf < 4; ++nf) {
        const int n = wn * 64 + nf * 16 + lr;
        const int c = (ks * 4 + kc) ^ (n & 7);
        bfr[nf] = *(const bf16x8*)((const char*)Bs + n * 128 + c * 16);
      }
      #pragma unroll
      for (int mf = 0; mf < 4; ++mf)
        #pragma unroll
        for (int nf = 0; nf < 4; ++nf)
          acc[mf][nf] = __builtin_amdgcn_mfma_f32_16x16x32_bf16(af[mf], bfr[nf], acc[mf][nf], 0, 0, 0);
    }
    __syncthreads();
  }
  #pragma unroll
  for (int mf = 0; mf < 4; ++mf) {
    const int row = m0 + wm * 64 + mf * 16 + (kc << 2);
    #pragma unroll
    for (int rr = 0; rr < 4; ++rr) {
      unsigned short* erow = eo + (size_t)(row + rr) * DDIM;
      #pragma unroll
      for (int nf = 0; nf < 4; ++nf) {
        const int col = n0 + wn * 64 + nf * 16 + lr;
        erow[col] = f2b(acc[mf][nf][rr]);
      }
    }
  }
}

// ---------------- combine: out[t] = w0*eo[row0] + w1*eo[row1] ----------------
__global__ void combine_k(const unsigned short* __restrict__ eo,
                          const int* __restrict__ trow, const float* __restrict__ sel_w,
                          float* __restrict__ out) {
  const int t = blockIdx.x;
  const int r0 = trow[t * 2], r1 = trow[t * 2 + 1];
  const float w0 = sel_w[t * 2], w1 = sel_w[t * 2 + 1];
  const int c = threadIdx.x * 8;
  union { uint4 u; unsigned short s[8]; } a, b;
  a.u = *(const uint4*)(eo + (size_t)r0 * DDIM + c);
  b.u = *(const uint4*)(eo + (size_t)r1 * DDIM + c);
  float o[8];
  #pragma unroll
  for (int j = 0; j < 8; ++j) {
    union { unsigned u; float f; } fa, fb;
    fa.u = (unsigned)a.s[j] << 16;
    fb.u = (unsigned)b.s[j] << 16;
    o[j] = w0 * fa.f + w1 * fb.f;
  }
  float4* dst = (float4*)(out + (size_t)t * DDIM + c);
  dst[0] = make_float4(o[0], o[1], o[2], o[3]);
  dst[1] = make_float4(o[4], o[5], o[6], o[7]);
}

// ---------------- launch ----------------
// ws layout (bytes)
#define OFF_CNT   0u
#define OFF_BASE  64u
#define OFF_SELE  4096u
#define OFF_SELW  36864u
#define OFF_RTOK  69632u
#define OFF_RGW   106496u
#define OFF_TROW  143360u
#define OFF_XC    1048576u              // 9216*2048 bf16 (eo aliases after gemm1)
#define OFF_HID   38797312u             // 9216*4096 bf16
#define OFF_WBUF  114294784u            // w13t: 8*8192*2048 bf16 = 268435456
#define OFF_W2T   382730240ull          // w2t:  8*2048*4096 bf16 = 134217728
#define WS_NEED   516947968ull          // OFF_W2T + w2t size

extern "C" void kernel_launch(void* const* d_in, const int* in_sizes, int n_in,
                              void* d_out, int out_size, void* d_ws, size_t ws_size,
                              hipStream_t stream) {
  const float* x  = (const float*)d_in[0];
  const float* gw = (const float*)d_in[1];
  const float* w1 = (const float*)d_in[2];
  const float* w3 = (const float*)d_in[3];
  const float* w2 = (const float*)d_in[4];
  float* out = (float*)d_out;
  char* ws = (char*)d_ws;

  int*   cnt   = (int*)(ws + OFF_CNT);
  int*   base  = (int*)(ws + OFF_BASE);
  int*   sel_e = (int*)(ws + OFF_SELE);
  float* sel_w = (float*)(ws + OFF_SELW);
  int*   rtok  = (int*)(ws + OFF_RTOK);
  float* rgw   = (float*)(ws + OFF_RGW);
  int*   trow  = (int*)(ws + OFF_TROW);
  unsigned short* xc   = (unsigned short*)(ws + OFF_XC);
  unsigned short* hid  = (unsigned short*)(ws + OFF_HID);
  unsigned short* wbuf = (unsigned short*)(ws + OFF_WBUF);
  unsigned short* w2t  = (unsigned short*)(ws + OFF_W2T);
  unsigned short* eo   = xc;   // xc is dead after gemm1; reuse for expert outputs

  const bool fused = (ws_size >= WS_NEED);

  gate_topk<<<T_TOK / 4, 256, 0, stream>>>(x, gw, sel_e, sel_w);
  build_lists<<<1, 256, 0, stream>>>(sel_e, sel_w, cnt, base, rtok, rgw, trow);
  // w13 conversion + x gather in one dispatch (independent work, both pre-gemm1)
  conv13_gather<<<CONV13_BLOCKS + MAXROWS, 256, 0, stream>>>(w1, w3, wbuf,
                                                             x, base, rtok, xc);

  if (fused) {
    // gemm1 (4608 blocks) co-dispatched with conv_w2 (4096 units x 4 tiles)
    gemm1_fused<<<FUSED_GRID, 256, 0, stream>>>(xc, wbuf, base, hid, w2, w2t);
    moe_gemm2<<<MAXMT * 16, 256, 0, stream>>>(hid, w2t, base, eo);
  } else {
    moe_gemm1<<<G1_GRID, 256, 0, stream>>>(xc, wbuf, base, hid);
    conv_w2<<<dim3(64, 32, 8), 256, 0, stream>>>(w2, wbuf);  // alias w13t (dead)
    moe_gemm2<<<MAXMT * 16, 256, 0, stream>>>(hid, wbuf, base, eo);
  }
  combine_k<<<T_TOK, 256, 0, stream>>>(eo, trow, sel_w, out);
}

// Round 11
// 746.975 us; speedup vs baseline: 1.2991x; 1.0321x over previous
//
#include <hip/hip_runtime.h>
#include <hip/hip_bf16.h>

#define T_TOK 4096
#define DDIM  2048
#define FDIM  4096
#define NEXP  8
#define MAXROWS 9216   // T*2 + 8*128 padding
#define MAXMT   72     // MAXROWS/128
#define G1_GRID (MAXMT * 64)        // 4608 gemm1 blocks
#define CONV13_BLOCKS 32768         // 16z * 32x * 64y tiles of 64x64
// fused grid: 512 groups of 17 = [9 gemm | 8 conv]; 17%8==9%8==1 keeps XCD map valid
#define FUSED_GRID (512 * 17)

typedef __attribute__((ext_vector_type(4))) float f32x4;
typedef __attribute__((ext_vector_type(8))) short bf16x8;

__device__ __forceinline__ unsigned short f2b(float f) {
  union { float f; unsigned u; } c; c.f = f;
  unsigned r = c.u + 0x7FFFu + ((c.u >> 16) & 1u);
  return (unsigned short)(r >> 16);
}

// async global->LDS, 16B per lane; LDS dest must be wave-uniform base (+lane*16 implicit)
__device__ __forceinline__ void gload_lds16(const void* g, void* l) {
  __builtin_amdgcn_global_load_lds((__attribute__((address_space(1))) void*)(g),
                                   (__attribute__((address_space(3))) void*)(l),
                                   16, 0, 0);
}

// 2D-chunked XCD block mapping: XCD x owns m-tiles [x*MT_PER, +MT_PER), sweeps n
// in groups of 4. B-panel reuse distance = 4 blocks (L2-hot); A-chunk L2/L3-resident.
__device__ __forceinline__ void xcd_map2d(int bid, int MT_PER, int NT, int& mt, int& nt) {
  const int xcd = bid & 7;
  const int li = bid >> 3;
  const int grp = MT_PER * 4;
  const int ng = li / grp;
  const int rem = li % grp;
  mt = xcd * MT_PER + (rem >> 2);
  nt = ng * 4 + (rem & 3);
}

// ---------------- gating: one wave per token ----------------
__global__ void gate_topk(const float* __restrict__ x, const float* __restrict__ gw,
                          int* __restrict__ sel_e, float* __restrict__ sel_w) {
  const int t = blockIdx.x * 4 + (threadIdx.x >> 6);
  const int l = threadIdx.x & 63;
  const float* xr = x + (size_t)t * DDIM;
  float acc[8];
  #pragma unroll
  for (int e = 0; e < 8; ++e) acc[e] = 0.f;
  for (int d = l; d < DDIM; d += 64) {
    const float xv = xr[d];
    const float* g = gw + d * 8;
    #pragma unroll
    for (int e = 0; e < 8; ++e) acc[e] = fmaf(xv, g[e], acc[e]);
  }
  #pragma unroll
  for (int e = 0; e < 8; ++e) {
    float v = acc[e];
    #pragma unroll
    for (int off = 32; off; off >>= 1) v += __shfl_xor(v, off, 64);
    acc[e] = v;
  }
  if (l == 0) {
    int e0 = 0; float v0 = acc[0];
    #pragma unroll
    for (int e = 1; e < 8; ++e) if (acc[e] > v0) { v0 = acc[e]; e0 = e; }
    int e1 = -1; float v1 = -1e30f;
    #pragma unroll
    for (int e = 0; e < 8; ++e) if (e != e0 && acc[e] > v1) { v1 = acc[e]; e1 = e; }
    const float ex = __expf(v1 - v0);
    const float w0 = 1.f / (1.f + ex);
    sel_e[t * 2] = e0; sel_e[t * 2 + 1] = e1;
    sel_w[t * 2] = w0; sel_w[t * 2 + 1] = ex * w0;
  }
}

// ---------------- per-expert lists (single block, 1024 threads) ----------------
__global__ void build_lists(const int* __restrict__ sel_e, const float* __restrict__ sel_w,
                            int* __restrict__ cnt, int* __restrict__ base,
                            int* __restrict__ row_token, float* __restrict__ row_gw,
                            int* __restrict__ trow) {
  __shared__ int c[8], f[8], b[9];
  const int tid = threadIdx.x;
  if (tid < 8) { c[tid] = 0; f[tid] = 0; }
  __syncthreads();
  for (int t = tid; t < T_TOK; t += 1024) {
    atomicAdd(&c[sel_e[t * 2]], 1);
    atomicAdd(&c[sel_e[t * 2 + 1]], 1);
  }
  __syncthreads();
  if (tid == 0) {
    int r = 0;
    for (int e = 0; e < 8; ++e) { b[e] = r; r += ((c[e] + 127) >> 7) << 7; }
    b[8] = r;
    for (int e = 0; e < 8; ++e) { cnt[e] = c[e]; base[e] = b[e]; }
    base[8] = r;
  }
  __syncthreads();
  for (int i = tid; i < MAXROWS; i += 1024) { row_token[i] = -1; row_gw[i] = 0.f; }
  __syncthreads();
  for (int t = tid; t < T_TOK; t += 1024) {
    #pragma unroll
    for (int k = 0; k < 2; ++k) {
      const int e = sel_e[t * 2 + k];
      const int p = b[e] + atomicAdd(&f[e], 1);
      row_token[p] = t; row_gw[p] = sel_w[t * 2 + k];
      trow[t * 2 + k] = p;                       // inverse map for combine
    }
  }
}

// ---------------- transpose + fp32->bf16 convert (shared tile passed in) ------------
// T padded to [64][70]: read stride 16*70*2B -> bank step 16 (2-way, free).
// dst row: interleave16 ? ((c>>4)*32 + rowAdd*16 + (c&15))   [w13: 16-granular pairing]
//                       : c                                   [w2: plain transpose]
__device__ __forceinline__ void conv_tile(const float* s, unsigned short* d,
                                          int R, int C, int interleave16, int rowAdd,
                                          int r0, int c0, int tid,
                                          unsigned short (*T)[70]) {
  {
    const int i = tid >> 2, jb = (tid & 3) * 16;
    #pragma unroll
    for (int k2 = 0; k2 < 4; ++k2) {
      const float4 v = *(const float4*)(s + (size_t)(r0 + i) * C + c0 + jb + k2 * 4);
      unsigned* p = (unsigned*)&T[i][jb + k2 * 4];
      p[0] = (unsigned)f2b(v.x) | ((unsigned)f2b(v.y) << 16);
      p[1] = (unsigned)f2b(v.z) | ((unsigned)f2b(v.w) << 16);
    }
  }
  __syncthreads();
  {
    const int j = tid >> 2, ib = (tid & 3) * 16;
    union { uint4 q[2]; unsigned short s16[16]; } pk;
    #pragma unroll
    for (int i = 0; i < 16; ++i) pk.s16[i] = T[ib + i][j];
    const int c = c0 + j;
    const int row = interleave16 ? (((c >> 4) << 5) + (rowAdd << 4) + (c & 15)) : c;
    unsigned short* drow = d + (size_t)row * R + r0 + ib;
    *(uint4*)drow = pk.q[0];
    *(uint4*)(drow + 8) = pk.q[1];
  }
}

// ---------------- conv_w13 tiles + gather_x rows in one dispatch --------------------
// blocks [0, CONV13_BLOCKS): w1/w3 -> w13t[e][8192][2048], 16-granular interleave:
//   row(f, w) = (f>>4)*32 + w*16 + (f&15)   (w: 0=w1, 1=w3)
// blocks [CONV13_BLOCKS, +MAXROWS): gather x rows -> compact bf16 xc
__global__ void conv13_gather(const float* __restrict__ w1, const float* __restrict__ w3,
                              unsigned short* __restrict__ dst,
                              const float* __restrict__ x, const int* __restrict__ base,
                              const int* __restrict__ row_token,
                              unsigned short* __restrict__ xc) {
  __shared__ unsigned short T[64][70];
  const int bid = blockIdx.x;
  if (bid < CONV13_BLOCKS) {
    const int z = bid >> 11;               // 0..15
    const int y = (bid >> 5) & 63;         // over F/64
    const int xg = bid & 31;               // over D/64
    const int e = z & 7;
    const int isw3 = z >> 3;
    const float* s = (isw3 ? w3 : w1) + (size_t)e * DDIM * FDIM;
    unsigned short* d = dst + (size_t)e * DDIM * FDIM * 2;
    conv_tile(s, d, DDIM, FDIM, 1, isw3, xg * 64, y * 64, threadIdx.x, T);
  } else {
    const int i = bid - CONV13_BLOCKS;
    if (i >= base[8]) return;
    const int t = row_token[i];
    const int tid = threadIdx.x;
    union { uint4 u; unsigned short s[8]; } o;
    if (t < 0) { o.u.x = 0u; o.u.y = 0u; o.u.z = 0u; o.u.w = 0u; }
    else {
      const float4* src = (const float4*)(x + (size_t)t * DDIM + tid * 8);
      const float4 a = src[0], bb = src[1];
      o.s[0] = f2b(a.x);  o.s[1] = f2b(a.y);  o.s[2] = f2b(a.z);  o.s[3] = f2b(a.w);
      o.s[4] = f2b(bb.x); o.s[5] = f2b(bb.y); o.s[6] = f2b(bb.z); o.s[7] = f2b(bb.w);
    }
    ((uint4*)(xc + (size_t)i * DDIM))[tid] = o.u;
  }
}

// standalone conv_w2 (fallback path when ws too small for overlap buffer)
__global__ void conv_w2(const float* __restrict__ w2, unsigned short* __restrict__ dst) {
  __shared__ unsigned short T[64][70];
  const int e = blockIdx.z;
  const float* s = w2 + (size_t)e * FDIM * DDIM;
  unsigned short* d = dst + (size_t)e * FDIM * DDIM;
  conv_tile(s, d, FDIM, DDIM, 0, 0, blockIdx.x * 64, blockIdx.y * 64, threadIdx.x, T);
}

// ---------------- GEMM1 body: 128x128 tile, BK=64, 4 waves, 2-barrier (proven) ------
// hidden = silu(x@w1) * (x@w3); B rows 16-granular interleaved: nf even = h, odd = g
// for the SAME 16 f-cols -> epilogue pairs acc[mf][2q]/acc[mf][2q+1] per-thread,
// zero shuffles, direct C-fragment stores (col=lane&15, row=(lane>>4)*4+rr, m89).
__device__ __forceinline__ void gemm1_body(int bid,
                                           const unsigned short* __restrict__ A,
                                           const unsigned short* __restrict__ B,
                                           const int* __restrict__ base,
                                           unsigned short* __restrict__ hid,
                                           unsigned short* As, unsigned short* Bs) {
  constexpr int KDIM = DDIM;      // 2048
  constexpr int NDIM = 2 * FDIM;  // 8192

  int mt, nt;
  xcd_map2d(bid, MAXMT / 8, NDIM / 128, mt, nt);

  const int m0 = mt * 128;
  if (m0 >= base[8]) return;
  int e = 0;
  #pragma unroll
  for (int qq = 1; qq < 8; ++qq) if (m0 >= base[qq]) e = qq;
  const int n0 = nt * 128;
  const unsigned short* Bp = B + (size_t)e * NDIM * KDIM;

  const int tid = threadIdx.x;
  const int l = tid & 63;
  const int w = tid >> 6;
  const int wm = w >> 1, wn = w & 1;
  const int lr = l & 15, kc = l >> 4;

  const f32x4 vzero = {0.f, 0.f, 0.f, 0.f};
  f32x4 acc[4][4];
  #pragma unroll
  for (int i = 0; i < 4; ++i)
    #pragma unroll
    for (int j = 0; j < 4; ++j) acc[i][j] = vzero;

  const int srow = w * 32 + (l >> 3);
  const int sc = l & 7;
  const unsigned short* Arow = A + (size_t)(m0 + srow) * KDIM;
  const unsigned short* Brow = Bp + (size_t)(n0 + srow) * KDIM;

  for (int k0 = 0; k0 < KDIM; k0 += 64) {
    #pragma unroll
    for (int qq = 0; qq < 4; ++qq) {
      const int r = srow + qq * 8;
      const int cg = (sc ^ (r & 7)) << 3;
      gload_lds16(Arow + (size_t)qq * 8 * KDIM + k0 + cg, As + w * 2048 + qq * 512);
      gload_lds16(Brow + (size_t)qq * 8 * KDIM + k0 + cg, Bs + w * 2048 + qq * 512);
    }
    __syncthreads();
    #pragma unroll
    for (int ks = 0; ks < 2; ++ks) {
      bf16x8 af[4], bfr[4];
      #pragma unroll
      for (int mf = 0; mf < 4; ++mf) {
        const int r = wm * 64 + mf * 16 + lr;
        const int c = (ks * 4 + kc) ^ (r & 7);
        af[mf] = *(const bf16x8*)((const char*)As + r * 128 + c * 16);
      }
      #pragma unroll
      for (int nf = 0; nf < 4; ++nf) {
        const int n = wn * 64 + nf * 16 + lr;
        const int c = (ks * 4 + kc) ^ (n & 7);
        bfr[nf] = *(const bf16x8*)((const char*)Bs + n * 128 + c * 16);
      }
      #pragma unroll
      for (int mf = 0; mf < 4; ++mf)
        #pragma unroll
        for (int nf = 0; nf < 4; ++nf)
          acc[mf][nf] = __builtin_amdgcn_mfma_f32_16x16x32_bf16(af[mf], bfr[nf], acc[mf][nf], 0, 0, 0);
    }
    __syncthreads();
  }

  // epilogue: nf even = h, nf odd = g (same 16 f-cols, same lane) -> no shuffles
  // f = (n0>>1) + wn*32 + q*16 + lr  for pair q = nf>>1
  const int fb = (n0 >> 1) + wn * 32;
  #pragma unroll
  for (int mf = 0; mf < 4; ++mf) {
    const int row = m0 + wm * 64 + mf * 16 + (kc << 2);
    #pragma unroll
    for (int q = 0; q < 2; ++q) {
      #pragma unroll
      for (int rr = 0; rr < 4; ++rr) {
        const float h = acc[mf][2 * q][rr];
        const float g = acc[mf][2 * q + 1][rr];
        const float res = (h / (1.f + __expf(-h))) * g;
        hid[(size_t)(row + rr) * FDIM + fb + q * 16 + lr] = f2b(res);
      }
    }
  }
}

// standalone gemm1 (fallback path)
__global__ void moe_gemm1(const unsigned short* __restrict__ A,
                          const unsigned short* __restrict__ B,
                          const int* __restrict__ base,
                          unsigned short* __restrict__ hid) {
  __shared__ __align__(16) unsigned short As[128 * 64];
  __shared__ __align__(16) unsigned short Bs[128 * 64];
  gemm1_body(blockIdx.x, A, B, base, hid, As, Bs);
}

// ---------------- fused: gemm1 blocks co-dispatched with conv_w2 work ---------------
// Per 17-block group: ids 0-8 -> gemm1, ids 9-16 -> conv_w2 unit (4 tiles each).
// conv writes w2t (separate ws region; no alias with w13t that gemm reads).
__global__ void gemm1_fused(const unsigned short* __restrict__ A,
                            const unsigned short* __restrict__ B,
                            const int* __restrict__ base,
                            unsigned short* __restrict__ hid,
                            const float* __restrict__ w2,
                            unsigned short* __restrict__ w2t) {
  __shared__ __align__(16) unsigned short As[128 * 64];
  __shared__ __align__(16) unsigned short Bs[128 * 64];
  const int g = blockIdx.x / 17;
  const int r = blockIdx.x % 17;
  if (r < 9) {
    gemm1_body(g * 9 + r, A, B, base, hid, As, Bs);
  } else {
    const int u = g * 8 + (r - 9);             // 0..4095
    unsigned short (*T)[70] = (unsigned short (*)[70])As;  // 8960B, fits in As
    #pragma unroll
    for (int j = 0; j < 4; ++j) {
      const int cid = u * 4 + j;               // 0..16383
      const int e = cid >> 11;                 // 2048 tiles per expert
      const int rem = cid & 2047;
      const int r0 = (rem >> 5) * 64;          // over F (4096)
      const int c0 = (rem & 31) * 64;          // over D (2048)
      conv_tile(w2 + (size_t)e * FDIM * DDIM, w2t + (size_t)e * FDIM * DDIM,
                FDIM, DDIM, 0, 0, r0, c0, threadIdx.x, T);
      __syncthreads();                         // T reused next iteration
    }
  }
}

// ---------------- GEMM2: 128x128 tile, 2-barrier; dense bf16 eo stores --------------
__global__ void moe_gemm2(const unsigned short* __restrict__ A,
                          const unsigned short* __restrict__ B,
                          const int* __restrict__ base,
                          unsigned short* __restrict__ eo) {
  constexpr int KDIM = FDIM;      // 4096
  constexpr int NDIM = DDIM;      // 2048

  int mt, ntl;
  xcd_map2d(blockIdx.x, MAXMT / 8, NDIM / 128, mt, ntl);

  const int m0 = mt * 128;
  if (m0 >= base[8]) return;
  int e = 0;
  #pragma unroll
  for (int qq = 1; qq < 8; ++qq) if (m0 >= base[qq]) e = qq;
  const int n0 = ntl * 128;
  const unsigned short* Bp = B + (size_t)e * NDIM * KDIM;

  __shared__ __align__(16) unsigned short As[128 * 64];
  __shared__ __align__(16) unsigned short Bs[128 * 64];

  const int tid = threadIdx.x;
  const int l = tid & 63;
  const int w = tid >> 6;
  const int wm = w >> 1, wn = w & 1;
  const int lr = l & 15, kc = l >> 4;

  const f32x4 vzero = {0.f, 0.f, 0.f, 0.f};
  f32x4 acc[4][4];
  #pragma unroll
  for (int i = 0; i < 4; ++i)
    #pragma unroll
    for (int j = 0; j < 4; ++j) acc[i][j] = vzero;

  const int srow = w * 32 + (l >> 3);
  const int sc = l & 7;
  const unsigned short* Arow = A + (size_t)(m0 + srow) * KDIM;
  const unsigned short* Brow = Bp + (size_t)(n0 + srow) * KDIM;

  for (int k0 = 0; k0 < KDIM; k0 += 64) {
    #pragma unroll
    for (int qq = 0; qq < 4; ++qq) {
      const int r = srow + qq * 8;
      const int cg = (sc ^ (r & 7)) << 3;
      gload_lds16(Arow + (size_t)qq * 8 * KDIM + k0 + cg,
                  (unsigned short*)As + w * 2048 + qq * 512);
      gload_lds16(Brow + (size_t)qq * 8 * KDIM + k0 + cg,
                  (unsigned short*)Bs + w * 2048 + qq * 512);
    }
    __syncthreads();
    #pragma unroll
    for (int ks = 0; ks < 2; ++ks) {
      bf16x8 af[4], bfr[4];
      #pragma unroll
      for (int mf = 0; mf < 4; ++mf) {
        const int r = wm * 64 + mf * 16 + lr;
        const int c = (ks * 4 + kc) ^ (r & 7);
        af[mf] = *(const bf16x8*)((const char*)As + r * 128 + c * 16);
      }
      #pragma unroll
      for (int nf = 0; nf < 4; ++nf) {
        const int n = wn * 64 + nf * 16 + lr;
        const int c = (ks * 4 + kc) ^ (n & 7);
        bfr[nf] = *(const bf16x8*)((const char*)Bs + n * 128 + c * 16);
      }
      #pragma unroll
      for (int mf = 0; mf < 4; ++mf)
        #pragma unroll
        for (int nf = 0; nf < 4; ++nf)
          acc[mf][nf] = __builtin_amdgcn_mfma_f32_16x16x32_bf16(af[mf], bfr[nf], acc[mf][nf], 0, 0, 0);
    }
    __syncthreads();
  }
  #pragma unroll
  for (int mf = 0; mf < 4; ++mf) {
    const int row = m0 + wm * 64 + mf * 16 + (kc << 2);
    #pragma unroll
    for (int rr = 0; rr < 4; ++rr) {
      unsigned short* erow = eo + (size_t)(row + rr) * DDIM;
      #pragma unroll
      for (int nf = 0; nf < 4; ++nf) {
        const int col = n0 + wn * 64 + nf * 16 + lr;
        erow[col] = f2b(acc[mf][nf][rr]);
      }
    }
  }
}

// ---------------- combine: out[t] = w0*eo[row0] + w1*eo[row1] (grid-stride) ---------
__global__ void combine_k(const unsigned short* __restrict__ eo,
                          const int* __restrict__ trow, const float* __restrict__ sel_w,
                          float* __restrict__ out) {
  for (int t = blockIdx.x; t < T_TOK; t += gridDim.x) {
    const int r0 = trow[t * 2], r1 = trow[t * 2 + 1];
    const float w0 = sel_w[t * 2], w1 = sel_w[t * 2 + 1];
    const int c = threadIdx.x * 8;
    union { uint4 u; unsigned short s[8]; } a, b;
    a.u = *(const uint4*)(eo + (size_t)r0 * DDIM + c);
    b.u = *(const uint4*)(eo + (size_t)r1 * DDIM + c);
    float o[8];
    #pragma unroll
    for (int j = 0; j < 8; ++j) {
      union { unsigned u; float f; } fa, fb;
      fa.u = (unsigned)a.s[j] << 16;
      fb.u = (unsigned)b.s[j] << 16;
      o[j] = w0 * fa.f + w1 * fb.f;
    }
    float4* dst = (float4*)(out + (size_t)t * DDIM + c);
    dst[0] = make_float4(o[0], o[1], o[2], o[3]);
    dst[1] = make_float4(o[4], o[5], o[6], o[7]);
  }
}

// ---------------- launch ----------------
// ws layout (bytes)
#define OFF_CNT   0u
#define OFF_BASE  64u
#define OFF_SELE  4096u
#define OFF_SELW  36864u
#define OFF_RTOK  69632u
#define OFF_RGW   106496u
#define OFF_TROW  143360u
#define OFF_XC    1048576u              // 9216*2048 bf16 (eo aliases after gemm1)
#define OFF_HID   38797312u             // 9216*4096 bf16
#define OFF_WBUF  114294784u            // w13t: 8*8192*2048 bf16 = 268435456
#define OFF_W2T   382730240ull          // w2t:  8*2048*4096 bf16 = 134217728
#define WS_NEED   516947968ull          // OFF_W2T + w2t size

extern "C" void kernel_launch(void* const* d_in, const int* in_sizes, int n_in,
                              void* d_out, int out_size, void* d_ws, size_t ws_size,
                              hipStream_t stream) {
  const float* x  = (const float*)d_in[0];
  const float* gw = (const float*)d_in[1];
  const float* w1 = (const float*)d_in[2];
  const float* w3 = (const float*)d_in[3];
  const float* w2 = (const float*)d_in[4];
  float* out = (float*)d_out;
  char* ws = (char*)d_ws;

  int*   cnt   = (int*)(ws + OFF_CNT);
  int*   base  = (int*)(ws + OFF_BASE);
  int*   sel_e = (int*)(ws + OFF_SELE);
  float* sel_w = (float*)(ws + OFF_SELW);
  int*   rtok  = (int*)(ws + OFF_RTOK);
  float* rgw   = (float*)(ws + OFF_RGW);
  int*   trow  = (int*)(ws + OFF_TROW);
  unsigned short* xc   = (unsigned short*)(ws + OFF_XC);
  unsigned short* hid  = (unsigned short*)(ws + OFF_HID);
  unsigned short* wbuf = (unsigned short*)(ws + OFF_WBUF);
  unsigned short* w2t  = (unsigned short*)(ws + OFF_W2T);
  unsigned short* eo   = xc;   // xc is dead after gemm1; reuse for expert outputs

  const bool fused = (ws_size >= WS_NEED);

  gate_topk<<<T_TOK / 4, 256, 0, stream>>>(x, gw, sel_e, sel_w);
  build_lists<<<1, 1024, 0, stream>>>(sel_e, sel_w, cnt, base, rtok, rgw, trow);
  // w13 conversion (16-granular interleave) + x gather in one dispatch
  conv13_gather<<<CONV13_BLOCKS + MAXROWS, 256, 0, stream>>>(w1, w3, wbuf,
                                                             x, base, rtok, xc);

  if (fused) {
    // gemm1 (4608 blocks) co-dispatched with conv_w2 (4096 units x 4 tiles)
    gemm1_fused<<<FUSED_GRID, 256, 0, stream>>>(xc, wbuf, base, hid, w2, w2t);
    moe_gemm2<<<MAXMT * 16, 256, 0, stream>>>(hid, w2t, base, eo);
  } else {
    moe_gemm1<<<G1_GRID, 256, 0, stream>>>(xc, wbuf, base, hid);
    conv_w2<<<dim3(64, 32, 8), 256, 0, stream>>>(w2, wbuf);  // alias w13t (dead)
    moe_gemm2<<<MAXMT * 16, 256, 0, stream>>>(hid, wbuf, base, eo);
  }
  combine_k<<<2048, 256, 0, stream>>>(eo, trow, sel_w, out);
}